// Round 7
// baseline (670.372 us; speedup 1.0000x reference)
//
#include <hip/hip_runtime.h>

#define B   64
#define KK  4096
#define D   256
#define Q   8
#define H   4
#define DH  64
#define HQ  32
#define HM  512
#define NCH 16
#define CHK 256
#define EPS 1e-8f
#define LNE 1e-5f
#define SCALE 0.125f

typedef short bf16x8 __attribute__((ext_vector_type(8)));
typedef float f32x4 __attribute__((ext_vector_type(4)));

#define MFMA __builtin_amdgcn_mfma_f32_16x16x32_bf16

__device__ __forceinline__ float bf2f(unsigned short u) {
    unsigned int x = ((unsigned int)u) << 16;
    float f; __builtin_memcpy(&f, &x, 4); return f;
}
__device__ __forceinline__ unsigned short f2bf(float f) {
    unsigned int x; __builtin_memcpy(&x, &f, 4);
    unsigned int lsb = (x >> 16) & 1u;
    x += 0x7fffu + lsb;
    return (unsigned short)(x >> 16);
}

// ---------------- fused prep: weight transforms + slots init ----------------
// wpk: W' = diag(ln_in_w)*[Wk*SCALE | Wv] packed as B-frags:
//   subtile s = ct*8+kt (ct 0..31, kt 0..7), elem i = lane*8+e:
//   col = ct*16 + (lane&15), k = kt*32 + (lane>>4)*8 + e
__global__ __launch_bounds__(256) void k_prep(
    const float* __restrict__ Wk, const float* __restrict__ Wv,
    const float* __restrict__ lnw, const float* __restrict__ lnb,
    const float* __restrict__ gWih, const float* __restrict__ gWhh,
    const float* __restrict__ W1, const float* __restrict__ W2,
    const float* __restrict__ Wq, const float* __restrict__ s0,
    unsigned short* __restrict__ wpk, float* __restrict__ cs, float* __restrict__ b2v,
    unsigned short* __restrict__ Wihbf, unsigned short* __restrict__ Whhbf,
    unsigned short* __restrict__ W1T, unsigned short* __restrict__ W2T,
    unsigned short* __restrict__ WqT, float* __restrict__ slots)
{
    const int blk = blockIdx.x, t = threadIdx.x;
    if (blk < 256) {                      // wpk subtiles
        const int ct = blk >> 3, kt = blk & 7;
#pragma unroll
        for (int e2 = 0; e2 < 2; ++e2) {
            const int i = t * 2 + e2;
            const int lane = i >> 3, e = i & 7;
            const int col = ct * 16 + (lane & 15);
            const int k = kt * 32 + (lane >> 4) * 8 + e;
            const float wv = lnw[k];
            const float v = (col < 256) ? wv * Wk[(size_t)k * 256 + col] * SCALE
                                        : wv * Wv[(size_t)k * 256 + (col - 256)];
            wpk[(size_t)blk * 512 + i] = f2bf(v);
        }
    } else if (blk < 258) {               // cs (colsum of W') and b2 (ln_in_b @ W)
        const int c = (blk - 256) * 256 + t;
        float s1 = 0.f, s2 = 0.f;
        for (int k = 0; k < 256; ++k) {
            const float wraw = (c < 256) ? Wk[(size_t)k * 256 + c] * SCALE
                                         : Wv[(size_t)k * 256 + (c - 256)];
            s1 += lnw[k] * wraw;
            s2 += lnb[k] * wraw;
        }
        cs[c] = s1; b2v[c] = s2;
    } else if (blk < 1026) {              // Wih cvt
        const int i = (blk - 258) * 256 + t;
        Wihbf[i] = f2bf(gWih[i]);
    } else if (blk < 1794) {              // Whh cvt
        const int i = (blk - 1026) * 256 + t;
        Whhbf[i] = f2bf(gWhh[i]);
    } else if (blk < 2306) {              // W1T [512][256]
        const int nn = blk - 1794;
        W1T[(size_t)nn * 256 + t] = f2bf(W1[(size_t)t * 512 + nn]);
    } else if (blk < 2562) {              // W2T [256][512]
        const int nn = blk - 2306;
        W2T[(size_t)nn * 512 + t]       = f2bf(W2[(size_t)t * 256 + nn]);
        W2T[(size_t)nn * 512 + 256 + t] = f2bf(W2[(size_t)(256 + t) * 256 + nn]);
    } else if (blk < 2818) {              // WqT [256][256]
        const int nn = blk - 2562;
        WqT[(size_t)nn * 256 + t] = f2bf(Wq[(size_t)t * 256 + nn]);
    } else {                              // slots init (512 blocks)
        const int i = (blk - 2818) * 256 + t;
        slots[i] = s0[i];
    }
}

// ---------------- K1: K/V projection, BARRIER-FREE ---------------
// A: wave-private LDS (16 rows each, raw bf16, LN folded into epilogue).
// B: fragments loaded DIRECTLY from L2 (wpk is 256KB, packed = frag layout).
// No __syncthreads anywhere; waves pipeline independently.
__global__ __launch_bounds__(256) void k1_mfma(
    const float* __restrict__ inp, const unsigned short* __restrict__ wpk,
    const float* __restrict__ cs, const float* __restrict__ b2v,
    unsigned short* __restrict__ kpk, unsigned short* __restrict__ vpk)
{
    __shared__ char abase[32768];       // 4 waves x 16 rows x 512B (wave-private)
    const int t = threadIdx.x, w = t >> 6, l = t & 63;
    const size_t row0 = (size_t)blockIdx.x * 64;
    const int b_blk = blockIdx.x >> 6;
    const int kbase = (blockIdx.x & 63) * 64;
    const int lg = l >> 4;

    // ---- load raw rows, compute stats, pack raw bf16 to LDS (swizzled)
    float4 xv[16];
#pragma unroll
    for (int i = 0; i < 16; ++i)
        xv[i] = ((const float4*)(inp + (row0 + w * 16 + i) * D))[l];
    float rsA = 0.f, muA = 0.f;         // lane holds (rs, rs*mu) of row w*16+(l&15)
#pragma unroll
    for (int i = 0; i < 16; ++i) {
        const int r = w * 16 + i;
        const float4 x = xv[i];
        float s  = x.x + x.y + x.z + x.w;
        float ss = x.x*x.x + x.y*x.y + x.z*x.z + x.w*x.w;
#pragma unroll
        for (int off = 32; off; off >>= 1) { s += __shfl_xor(s, off); ss += __shfl_xor(ss, off); }
        const float mu = s * (1.f / 256.f);
        const float rs = rsqrtf(ss * (1.f / 256.f) - mu * mu + LNE);
        if ((l & 15) == i) { rsA = rs; muA = rs * mu; }
        ushort4 pk;
        pk.x = f2bf(x.x); pk.y = f2bf(x.y); pk.z = f2bf(x.z); pk.w = f2bf(x.w);
        *(ushort4*)(abase + r * 512 + ((l * 8) ^ ((r & 7) << 4))) = pk;
    }

    // ---- hoist A fragments (wave-private rows; lgkmcnt only, no barrier)
    const int arow = w * 16 + (l & 15);
    const char* ap = abase + arow * 512;
    const int asw = (l & 7) << 4;
    bf16x8 af[8];
#pragma unroll
    for (int kk = 0; kk < 8; ++kk)
        af[kk] = *(const bf16x8*)(ap + ((kk * 64 + lg * 16) ^ asw));
    // V-half row stats (rows w*16 + lg*4 + r)
    float rsV[4], muV[4];
#pragma unroll
    for (int r = 0; r < 4; ++r) {
        rsV[r] = __shfl(rsA, lg * 4 + r);
        muV[r] = __shfl(muA, lg * 4 + r);
    }

    const f32x4 fz = {0.f, 0.f, 0.f, 0.f};
    // ---- K half: C[d][k] via swapped operands; B frags direct from L2
#pragma unroll 2
    for (int n2 = 0; n2 < 8; ++n2) {
        const char* bsub = (const char*)wpk + (size_t)n2 * 16384 + l * 16;
        f32x4 acc[2] = {fz, fz};
#pragma unroll
        for (int kk = 0; kk < 8; ++kk) {
            const bf16x8 b0 = *(const bf16x8*)(bsub + kk * 1024);
            const bf16x8 b1 = *(const bf16x8*)(bsub + 8192 + kk * 1024);
            acc[0] = MFMA(b0, af[kk], acc[0], 0, 0, 0);
            acc[1] = MFMA(b1, af[kk], acc[1], 0, 0, 0);
        }
        const int kt16 = (kbase >> 4) + w;
#pragma unroll
        for (int nf = 0; nf < 2; ++nf) {
            const int d0 = n2 * 32 + nf * 16 + lg * 4;
            const float4 cs4 = *(const float4*)(cs + d0);
            const float4 bb4 = *(const float4*)(b2v + d0);
            unsigned short* kp = kpk
                + ((((size_t)b_blk * 256 + kt16) * 8 + n2) * 512)
                + ((l & 15) + ((nf * 2 + (lg >> 1)) << 4)) * 8 + (lg & 1) * 4;
            ushort4 pk;
            pk.x = f2bf(rsA * acc[nf][0] - muA * cs4.x + bb4.x);
            pk.y = f2bf(rsA * acc[nf][1] - muA * cs4.y + bb4.y);
            pk.z = f2bf(rsA * acc[nf][2] - muA * cs4.z + bb4.z);
            pk.w = f2bf(rsA * acc[nf][3] - muA * cs4.w + bb4.w);
            *(ushort4*)kp = pk;
        }
    }
    // ---- V half: C[k][d] normal orientation
#pragma unroll 2
    for (int n2 = 8; n2 < 16; ++n2) {
        const char* bsub = (const char*)wpk + (size_t)n2 * 16384 + l * 16;
        f32x4 acc[2] = {fz, fz};
#pragma unroll
        for (int kk = 0; kk < 8; ++kk) {
            const bf16x8 b0 = *(const bf16x8*)(bsub + kk * 1024);
            const bf16x8 b1 = *(const bf16x8*)(bsub + 8192 + kk * 1024);
            acc[0] = MFMA(af[kk], b0, acc[0], 0, 0, 0);
            acc[1] = MFMA(af[kk], b1, acc[1], 0, 0, 0);
        }
        const int kt32 = (kbase >> 5) + (w >> 1);
#pragma unroll
        for (int nf = 0; nf < 2; ++nf) {
            const int c = n2 * 32 + nf * 16 + (l & 15);   // 256..511
            const float csc = cs[c], b2c = b2v[c];
            const int dt16 = (n2 - 8) * 2 + nf;
            unsigned short* vp = vpk
                + ((((size_t)b_blk * 128 + kt32) * 16 + dt16) * 512)
                + ((l & 15) + (((w & 1) * 2 + (lg >> 1)) << 4)) * 8 + (lg & 1) * 4;
            ushort4 pk;
            pk.x = f2bf(rsV[0] * acc[nf][0] - muV[0] * csc + b2c);
            pk.y = f2bf(rsV[1] * acc[nf][1] - muV[1] * csc + b2c);
            pk.z = f2bf(rsV[2] * acc[nf][2] - muV[2] * csc + b2c);
            pk.w = f2bf(rsV[3] * acc[nf][3] - muV[3] * csc + b2c);
            *(ushort4*)vp = pk;
        }
    }
}

// ---------------- K2: LN(slots) + q projection (iter 0 only) ----------------
__global__ __launch_bounds__(256) void k2_qproj(
    const float* __restrict__ slots, const float* __restrict__ Wq,
    const float* __restrict__ lnw, const float* __restrict__ lnb, float* __restrict__ qbuf)
{
    const int row = blockIdx.x, t = threadIdx.x;
    __shared__ float sn[256];
    __shared__ float red[8];
    const float x = slots[(size_t)row * D + t];
    float mu, rs;
    {
        float s = x, ss = x * x;
#pragma unroll
        for (int off = 32; off; off >>= 1) { s += __shfl_xor(s, off); ss += __shfl_xor(ss, off); }
        if ((t & 63) == 0) { red[t >> 6] = s; red[4 + (t >> 6)] = ss; }
        __syncthreads();
        const float S  = red[0] + red[1] + red[2] + red[3];
        const float SS = red[4] + red[5] + red[6] + red[7];
        mu = S * (1.f / 256.f);
        rs = rsqrtf(SS * (1.f / 256.f) - mu * mu + LNE);
    }
    sn[t] = (x - mu) * rs * lnw[t] + lnb[t];
    __syncthreads();
    float acc = 0.f;
    for (int d = 0; d < 256; ++d) acc = fmaf(sn[d], Wq[(size_t)d * 256 + t], acc);
    qbuf[(size_t)row * D + t] = acc;
}

// ---------------- fused attention: packed K/V, sum-only softmax -------------
__global__ __launch_bounds__(256) void k_attn(
    const unsigned short* __restrict__ kpk, const unsigned short* __restrict__ vpk,
    const float* __restrict__ qbuf, float* __restrict__ updp,
    float* __restrict__ denp, float* __restrict__ pbuf, int write_p)
{
    __shared__ unsigned short psm[2][2048];
    __shared__ float dred[4][32];
    const int t = threadIdx.x, w = t >> 6, l = t & 63;
    const int b = blockIdx.x >> 4, chunk = blockIdx.x & 15;
    const int k0g = chunk * CHK;
    const int n = l & 15, lg = l >> 4;

    bf16x8 qf[2][2];
#pragma unroll
    for (int p = 0; p < 2; ++p) {
        const int h = p * 2 + (n >> 3);
        const float* qb = qbuf + ((size_t)b * Q + (n & 7)) * D;
#pragma unroll
        for (int j = 0; j < 2; ++j) {
            const int dbase = (h * 2 + j) * 32 + lg * 8;
            short tmp[8];
#pragma unroll
            for (int e = 0; e < 8; ++e) tmp[e] = (short)f2bf(qb[dbase + e]);
            __builtin_memcpy(&qf[p][j], tmp, 16);
        }
    }
    const bf16x8 ZV = {0,0,0,0,0,0,0,0};
    const f32x4 fz = {0.f,0.f,0.f,0.f};
    f32x4 pv[2][4];
#pragma unroll
    for (int mt = 0; mt < 2; ++mt)
#pragma unroll
        for (int nf = 0; nf < 4; ++nf) pv[mt][nf] = fz;
    float den0 = 0.f, den1 = 0.f;

    const unsigned short* kb0 = kpk + (((size_t)(b * 256 + chunk * 16 + w)) * 8) * 512 + l * 8;
    const unsigned short* vb0 = vpk + (((size_t)(b * 128 + chunk * 8) * 16) + w * 4) * 512 + l * 8;

    for (int tile = 0; tile < 4; ++tile) {
        bf16x8 kf[8];
#pragma unroll
        for (int kk = 0; kk < 8; ++kk)
            kf[kk] = *(const bf16x8*)(kb0 + (size_t)tile * 16384 + kk * 512);
        f32x4 lac[2] = {fz, fz};
#pragma unroll
        for (int kk = 0; kk < 8; ++kk) {
            const int p = kk >> 2;
            const bool on = (((kk & 3) >> 1) == (n >> 3));
            const bf16x8 bq = on ? qf[p][kk & 1] : ZV;
            if (p == 0) lac[0] = MFMA(kf[kk], bq, lac[0], 0, 0, 0);
            else        lac[1] = MFMA(kf[kk], bq, lac[1], 0, 0, 0);
        }
        // joint softmax over 32 (h,q) per k-row; no max-sub (|logit| ~ O(1))
#pragma unroll
        for (int reg = 0; reg < 4; ++reg) {
            const float e0 = __expf(lac[0][reg]);
            const float e1 = __expf(lac[1][reg]);
            float se = e0 + e1;
#pragma unroll
            for (int off = 8; off; off >>= 1) se += __shfl_xor(se, off);
            const float inv = 1.f / se;
            lac[0][reg] = e0 * inv; lac[1][reg] = e1 * inv;
            den0 += lac[0][reg];    den1 += lac[1][reg];
        }
        char* pb = (char*)psm[tile & 1];
        const int kb = w * 16 + lg * 4;
        {
            ushort4 p0, p1;
            p0.x = f2bf(lac[0][0]); p0.y = f2bf(lac[0][1]); p0.z = f2bf(lac[0][2]); p0.w = f2bf(lac[0][3]);
            p1.x = f2bf(lac[1][0]); p1.y = f2bf(lac[1][1]); p1.z = f2bf(lac[1][2]); p1.w = f2bf(lac[1][3]);
            *(ushort4*)(pb + n * 128 + ((kb * 2) ^ ((n & 7) << 4))) = p0;
            *(ushort4*)(pb + (16 + n) * 128 + ((kb * 2) ^ ((n & 7) << 4))) = p1;
        }
        if (write_p) {
            float* pp = pbuf + ((size_t)b * KK + k0g + tile * 64 + kb) * HQ;
#pragma unroll
            for (int reg = 0; reg < 4; ++reg) {
                pp[(size_t)reg * HQ + n] = lac[0][reg];
                pp[(size_t)reg * HQ + 16 + n] = lac[1][reg];
            }
        }
        __syncthreads();
        // PV: V frags on-demand from packed global (R5 style — low VGPR)
#pragma unroll
        for (int kkp = 0; kkp < 2; ++kkp) {
            const int koff = kkp * 64 + lg * 16;
            const bf16x8 a0 = *(const bf16x8*)(pb + n * 128 + (koff ^ ((n & 7) << 4)));
            const bf16x8 a1 = *(const bf16x8*)(pb + (16 + n) * 128 + (koff ^ ((n & 7) << 4)));
#pragma unroll
            for (int nf = 0; nf < 4; ++nf) {
                const bf16x8 bv = *(const bf16x8*)(vb0 + (tile * 32 + kkp * 16 + nf) * 512);
                pv[0][nf] = MFMA(a0, bv, pv[0][nf], 0, 0, 0);
                pv[1][nf] = MFMA(a1, bv, pv[1][nf], 0, 0, 0);
            }
        }
    }

    den0 += __shfl_xor(den0, 16); den0 += __shfl_xor(den0, 32);
    den1 += __shfl_xor(den1, 16); den1 += __shfl_xor(den1, 32);
    if (l < 16) { dred[w][l] = den0; dred[w][16 + l] = den1; }
    __syncthreads();
    if (t < 32)
        denp[((size_t)b * NCH + chunk) * HQ + t] =
            dred[0][t] + dred[1][t] + dred[2][t] + dred[3][t];

    if ((lg >> 1) == (w & 1)) {
        const int mt = w >> 1;
#pragma unroll
        for (int nf = 0; nf < 4; ++nf) {
#pragma unroll
            for (int reg = 0; reg < 4; ++reg) {
                const int q = (lg & 1) * 4 + reg;
                updp[(((size_t)b * NCH + chunk) * Q + q) * D + w * 64 + nf * 16 + n] = pv[mt][nf][reg];
            }
        }
    }
}

// ---------------- LN helper for k_slot ----------------
__device__ __forceinline__ void ln_rows(const f32x4 sv[4], char* dstA, float* red,
    const float* __restrict__ lnw, const float* __restrict__ lnb,
    int w, int n, int lg, int col0)
{
    float ps[4], pq[4];
#pragma unroll
    for (int r = 0; r < 4; ++r) {
        float s = 0.f, q2 = 0.f;
#pragma unroll
        for (int nf = 0; nf < 4; ++nf) { const float v = sv[nf][r]; s += v; q2 += v * v; }
#pragma unroll
        for (int off = 1; off < 16; off <<= 1) { s += __shfl_xor(s, off); q2 += __shfl_xor(q2, off); }
        ps[r] = s; pq[r] = q2;
    }
    if (n == 0) {
#pragma unroll
        for (int r = 0; r < 4; ++r) {
            red[(lg * 4 + r) * 8 + w * 2]     = ps[r];
            red[(lg * 4 + r) * 8 + w * 2 + 1] = pq[r];
        }
    }
    __syncthreads();
    float mu[4], rs[4];
#pragma unroll
    for (int r = 0; r < 4; ++r) {
        const int rowm = lg * 4 + r;
        const float S  = red[rowm*8+0] + red[rowm*8+2] + red[rowm*8+4] + red[rowm*8+6];
        const float SS = red[rowm*8+1] + red[rowm*8+3] + red[rowm*8+5] + red[rowm*8+7];
        mu[r] = S * (1.f / 256.f);
        rs[r] = rsqrtf(SS * (1.f / 256.f) - mu[r] * mu[r] + LNE);
    }
#pragma unroll
    for (int nf = 0; nf < 4; ++nf) {
        const int col = col0 + nf * 16;
        const float wv = lnw[col], bv = lnb[col];
#pragma unroll
        for (int r = 0; r < 4; ++r) {
            const int rowm = lg * 4 + r;
            const float mval = (sv[nf][r] - mu[r]) * rs[r] * wv + bv;
            *(unsigned short*)(dstA + rowm * 512 + ((col * 2) ^ ((rowm & 7) << 4))) = f2bf(mval);
        }
    }
}

// ---------------- fused slot update: reduce+GRU+LN+MLP+LN+qproj -------------
__global__ __launch_bounds__(256) void k_slot(
    const float* __restrict__ updp, const float* __restrict__ denp,
    float* __restrict__ slots,
    const unsigned short* __restrict__ Wihbf, const unsigned short* __restrict__ Whhbf,
    const float* __restrict__ bih, const float* __restrict__ bhh,
    const unsigned short* __restrict__ W1T, const float* __restrict__ b1,
    const unsigned short* __restrict__ W2T, const float* __restrict__ b2,
    const float* __restrict__ lnmw, const float* __restrict__ lnmb,
    const unsigned short* __restrict__ WqT,
    const float* __restrict__ lnsw, const float* __restrict__ lnsb,
    float* __restrict__ qbuf, float* __restrict__ outp)
{
    __shared__ char sm[34304];
    unsigned short* uA = (unsigned short*)(sm);
    unsigned short* hA = (unsigned short*)(sm + 8192);
    float* hf32        = (float*)(sm + 16384);
    char*  hidA        = sm + 16384;
    float* dsum        = (float*)(sm + 33280);
    float* red         = (float*)(sm + 33536);
    const int t = threadIdx.x, w = t >> 6, l = t & 63;
    const int n = l & 15, lg = l >> 4;
    const int R0 = blockIdx.x * 16;
    const f32x4 fz = {0.f, 0.f, 0.f, 0.f};

    {
        float us[16];
#pragma unroll
        for (int m = 0; m < 16; ++m) {
            const int gr = R0 + m, bb = gr >> 3, q = gr & 7;
            float s = 0.f;
#pragma unroll
            for (int c = 0; c < 16; ++c)
                s += updp[(((size_t)(bb * 16 + c)) * 8 + q) * 256 + t];
            us[m] = s;
        }
        if (t < 64) {
            const int m = t >> 2, h = t & 3;
            const int gr = R0 + m, bb = gr >> 3, q = gr & 7;
            float s = 0.f;
#pragma unroll
            for (int c = 0; c < 16; ++c)
                s += denp[(size_t)(bb * 16 + c) * 32 + h * 8 + q];
            dsum[m * 4 + h] = s;
        }
#pragma unroll
        for (int m = 0; m < 16; ++m) {
            const float hv = slots[(size_t)(R0 + m) * 256 + t];
            hf32[m * 264 + t] = hv;
            *(unsigned short*)((char*)hA + m * 512 + ((t * 2) ^ ((m & 7) << 4))) = f2bf(hv);
        }
        __syncthreads();
        const int h = t >> 6;
#pragma unroll
        for (int m = 0; m < 16; ++m) {
            const float inv = 1.f / (dsum[m * 4 + h] + (float)KK * EPS);
            *(unsigned short*)((char*)uA + m * 512 + ((t * 2) ^ ((m & 7) << 4))) = f2bf(us[m] * inv);
        }
    }
    __syncthreads();

    f32x4 sv[4];
    {
        f32x4 ai0[4], ai1[4], ai2[4];
#pragma unroll
        for (int nf = 0; nf < 4; ++nf) { ai0[nf] = fz; ai1[nf] = fz; ai2[nf] = fz; }
#pragma unroll
        for (int kk = 0; kk < 8; ++kk) {
            const bf16x8 au = *(const bf16x8*)((char*)uA + n * 512 + ((kk * 64 + lg * 16) ^ ((n & 7) << 4)));
            const int kidx = kk * 32 + lg * 8;
#pragma unroll
            for (int nf = 0; nf < 4; ++nf) {
                const int col = w * 64 + nf * 16 + n;
                const bf16x8 br = *(const bf16x8*)(Wihbf + (size_t)col * 256 + kidx);
                const bf16x8 bz = *(const bf16x8*)(Wihbf + (size_t)(256 + col) * 256 + kidx);
                const bf16x8 bn = *(const bf16x8*)(Wihbf + (size_t)(512 + col) * 256 + kidx);
                ai0[nf] = MFMA(au, br, ai0[nf], 0, 0, 0);
                ai1[nf] = MFMA(au, bz, ai1[nf], 0, 0, 0);
                ai2[nf] = MFMA(au, bn, ai2[nf], 0, 0, 0);
            }
        }
        f32x4 ah0[4], ah1[4], ah2[4];
#pragma unroll
        for (int nf = 0; nf < 4; ++nf) { ah0[nf] = fz; ah1[nf] = fz; ah2[nf] = fz; }
#pragma unroll
        for (int kk = 0; kk < 8; ++kk) {
            const bf16x8 ah_ = *(const bf16x8*)((char*)hA + n * 512 + ((kk * 64 + lg * 16) ^ ((n & 7) << 4)));
            const int kidx = kk * 32 + lg * 8;
#pragma unroll
            for (int nf = 0; nf < 4; ++nf) {
                const int col = w * 64 + nf * 16 + n;
                const bf16x8 cr = *(const bf16x8*)(Whhbf + (size_t)col * 256 + kidx);
                const bf16x8 cz = *(const bf16x8*)(Whhbf + (size_t)(256 + col) * 256 + kidx);
                const bf16x8 cn = *(const bf16x8*)(Whhbf + (size_t)(512 + col) * 256 + kidx);
                ah0[nf] = MFMA(ah_, cr, ah0[nf], 0, 0, 0);
                ah1[nf] = MFMA(ah_, cz, ah1[nf], 0, 0, 0);
                ah2[nf] = MFMA(ah_, cn, ah2[nf], 0, 0, 0);
            }
        }
#pragma unroll
        for (int nf = 0; nf < 4; ++nf) {
            const int col = w * 64 + nf * 16 + n;
            const float br_ = bih[col], bz_ = bih[256 + col], bn_ = bih[512 + col];
            const float cr_ = bhh[col], cz_ = bhh[256 + col], cn_ = bhh[512 + col];
#pragma unroll
            for (int r = 0; r < 4; ++r) {
                const int rowm = lg * 4 + r;
                const float ir = ai0[nf][r] + br_, iz = ai1[nf][r] + bz_, inn = ai2[nf][r] + bn_;
                const float hr = ah0[nf][r] + cr_, hz = ah1[nf][r] + cz_, hn = ah2[nf][r] + cn_;
                const float rg = 1.f / (1.f + __expf(-(ir + hr)));
                const float zg = 1.f / (1.f + __expf(-(iz + hz)));
                const float ng = tanhf(inn + rg * hn);
                const float h0v = hf32[rowm * 264 + col];
                sv[nf][r] = (1.f - zg) * ng + zg * h0v;
            }
        }
    }
    ln_rows(sv, (char*)uA, red, lnmw, lnmb, w, n, lg, w * 64 + n);
    __syncthreads();

    {
        f32x4 m1[8];
#pragma unroll
        for (int nf = 0; nf < 8; ++nf) m1[nf] = fz;
#pragma unroll
        for (int kk = 0; kk < 8; ++kk) {
            const bf16x8 a = *(const bf16x8*)((char*)uA + n * 512 + ((kk * 64 + lg * 16) ^ ((n & 7) << 4)));
            const int kidx = kk * 32 + lg * 8;
#pragma unroll
            for (int nf = 0; nf < 8; ++nf) {
                const int colh = w * 128 + nf * 16 + n;
                const bf16x8 bb = *(const bf16x8*)(W1T + (size_t)colh * 256 + kidx);
                m1[nf] = MFMA(a, bb, m1[nf], 0, 0, 0);
            }
        }
        __syncthreads();
#pragma unroll
        for (int nf = 0; nf < 8; ++nf) {
            const int colh = w * 128 + nf * 16 + n;
            const float bb = b1[colh];
#pragma unroll
            for (int r = 0; r < 4; ++r) {
                const int rowm = lg * 4 + r;
                *(unsigned short*)(hidA + rowm * 1024 + ((colh * 2) ^ ((rowm & 7) << 4)))
                    = f2bf(fmaxf(m1[nf][r] + bb, 0.f));
            }
        }
    }
    __syncthreads();

    {
        f32x4 m2[4];
#pragma unroll
        for (int nf = 0; nf < 4; ++nf) m2[nf] = fz;
#pragma unroll
        for (int kk = 0; kk < 16; ++kk) {
            const bf16x8 a = *(const bf16x8*)(hidA + n * 1024 + ((kk * 64 + lg * 16) ^ ((n & 7) << 4)));
            const int kidx = kk * 32 + lg * 8;
#pragma unroll
            for (int nf = 0; nf < 4; ++nf) {
                const int col = w * 64 + nf * 16 + n;
                const bf16x8 bb = *(const bf16x8*)(W2T + (size_t)col * 512 + kidx);
                m2[nf] = MFMA(a, bb, m2[nf], 0, 0, 0);
            }
        }
#pragma unroll
        for (int nf = 0; nf < 4; ++nf) {
            const int col = w * 64 + nf * 16 + n;
            const float bb = b2[col];
#pragma unroll
            for (int r = 0; r < 4; ++r) {
                const int rowm = lg * 4 + r;
                const float v = m2[nf][r] + bb + sv[nf][r];
                sv[nf][r] = v;
                slots[(size_t)(R0 + rowm) * 256 + col] = v;
                if (outp) outp[(size_t)(R0 + rowm) * 256 + col] = v;
            }
        }
    }
    ln_rows(sv, (char*)hA, red, lnsw, lnsb, w, n, lg, w * 64 + n);
    __syncthreads();

    {
        f32x4 qa[4];
#pragma unroll
        for (int nf = 0; nf < 4; ++nf) qa[nf] = fz;
#pragma unroll
        for (int kk = 0; kk < 8; ++kk) {
            const bf16x8 a = *(const bf16x8*)((char*)hA + n * 512 + ((kk * 64 + lg * 16) ^ ((n & 7) << 4)));
            const int kidx = kk * 32 + lg * 8;
#pragma unroll
            for (int nf = 0; nf < 4; ++nf) {
                const int col = w * 64 + nf * 16 + n;
                const bf16x8 bb = *(const bf16x8*)(WqT + (size_t)col * 256 + kidx);
                qa[nf] = MFMA(a, bb, qa[nf], 0, 0, 0);
            }
        }
#pragma unroll
        for (int nf = 0; nf < 4; ++nf) {
            const int col = w * 64 + nf * 16 + n;
#pragma unroll
            for (int r = 0; r < 4; ++r)
                qbuf[(size_t)(R0 + lg * 4 + r) * 256 + col] = qa[nf][r];
        }
    }
}

// ---------------- attn output (invden computed inline) ----------------------
__global__ __launch_bounds__(256) void k7_attnout(
    const float* __restrict__ pbuf, const float* __restrict__ denp, float* __restrict__ out2)
{
    const int blk = blockIdx.x;
    const int b = blk >> 4;
    const int kk0 = (blk & 15) * 256;
    __shared__ float ps[256][33];
    __shared__ float inv[32];
    const int t = threadIdx.x;
    const float* pp = pbuf + ((size_t)b * KK + kk0) * HQ;
    for (int i = 0; i < 32; ++i) {
        const int idx = i * 256 + t;
        ps[idx >> 5][idx & 31] = pp[idx];
    }
    if (t < 32) {
        float s = 0.f;
#pragma unroll
        for (int c = 0; c < NCH; ++c) s += denp[((size_t)b * NCH + c) * HQ + t];
        inv[t] = 1.f / (s + (float)KK * EPS);
    }
    __syncthreads();
    float* o = out2 + (size_t)b * Q * KK + kk0 + t;
#pragma unroll
    for (int q = 0; q < 8; ++q) {
        float v = 0.f;
#pragma unroll
        for (int hh = 0; hh < 4; ++hh)
            v += (ps[t][hh * 8 + q] + EPS) * inv[hh * 8 + q];
        o[(size_t)q * KK] = v * 0.25f;
    }
}

extern "C" void kernel_launch(void* const* d_in, const int* in_sizes, int n_in,
                              void* d_out, int out_size, void* d_ws, size_t ws_size,
                              hipStream_t stream)
{
    const float* inputs  = (const float*)d_in[0];
    const float* slots0  = (const float*)d_in[1];
    const float* Wq      = (const float*)d_in[2];
    const float* Wk      = (const float*)d_in[3];
    const float* Wv      = (const float*)d_in[4];
    const float* ln_in_w = (const float*)d_in[5];
    const float* ln_in_b = (const float*)d_in[6];
    const float* ln_s_w  = (const float*)d_in[7];
    const float* ln_s_b  = (const float*)d_in[8];
    const float* ln_m_w  = (const float*)d_in[9];
    const float* ln_m_b  = (const float*)d_in[10];
    const float* gWih    = (const float*)d_in[11];
    const float* gWhh    = (const float*)d_in[12];
    const float* gbih    = (const float*)d_in[13];
    const float* gbhh    = (const float*)d_in[14];
    const float* W1      = (const float*)d_in[15];
    const float* b1      = (const float*)d_in[16];
    const float* W2      = (const float*)d_in[17];
    const float* b2      = (const float*)d_in[18];

    char* p = (char*)d_ws;
    unsigned short* kpk   = (unsigned short*)p; p += (size_t)B * KK * D * 2;
    unsigned short* vpk   = (unsigned short*)p; p += (size_t)B * KK * D * 2;
    float* pbuf   = (float*)p; p += (size_t)B * KK * HQ * 4;
    float* updp   = (float*)p; p += (size_t)B * NCH * Q * D * 4;
    float* denp   = (float*)p; p += (size_t)B * NCH * HQ * 4;
    float* qbuf   = (float*)p; p += (size_t)B * Q * D * 4;
    float* slots  = (float*)p; p += (size_t)B * Q * D * 4;
    unsigned short* wpk   = (unsigned short*)p; p += (size_t)512 * 256 * 2;
    float* csv    = (float*)p; p += 512 * 4;
    float* b2vv   = (float*)p; p += 512 * 4;
    unsigned short* Wihbf = (unsigned short*)p; p += (size_t)768 * 256 * 2;
    unsigned short* Whhbf = (unsigned short*)p; p += (size_t)768 * 256 * 2;
    unsigned short* W1T   = (unsigned short*)p; p += (size_t)HM * 256 * 2;
    unsigned short* W2T   = (unsigned short*)p; p += (size_t)256 * HM * 2;
    unsigned short* WqT   = (unsigned short*)p; p += (size_t)256 * 256 * 2;

    k_prep<<<3330, 256, 0, stream>>>(Wk, Wv, ln_in_w, ln_in_b, gWih, gWhh, W1, W2, Wq, slots0,
                                     wpk, csv, b2vv, Wihbf, Whhbf, W1T, W2T, WqT, slots);
    k1_mfma<<<(B * KK) / 64, 256, 0, stream>>>(inputs, wpk, csv, b2vv, kpk, vpk);
    k2_qproj<<<B * Q, 256, 0, stream>>>(slots, Wq, ln_s_w, ln_s_b, qbuf);
    for (int it = 0; it < 3; ++it) {
        k_attn<<<B * NCH, 256, 0, stream>>>(kpk, vpk, qbuf, updp, denp, pbuf, (it == 2) ? 1 : 0);
        k_slot<<<32, 256, 0, stream>>>(updp, denp, slots, Wihbf, Whhbf, gbih, gbhh,
                                       W1T, b1, W2T, b2, ln_m_w, ln_m_b, WqT,
                                       ln_s_w, ln_s_b, qbuf,
                                       (it == 2) ? (float*)d_out : (float*)nullptr);
    }
    k7_attnout<<<B * (KK / 256), 256, 0, stream>>>(pbuf, denp, (float*)d_out + (size_t)B * Q * D);
}

// Round 8
// 577.101 us; speedup vs baseline: 1.1616x; 1.1616x over previous
//
#include <hip/hip_runtime.h>

#define B   64
#define KK  4096
#define D   256
#define Q   8
#define H   4
#define DH  64
#define HQ  32
#define HM  512
#define NCH 8
#define CHK 512
#define EPS 1e-8f
#define LNE 1e-5f
#define SCALE 0.125f

typedef short bf16x8 __attribute__((ext_vector_type(8)));
typedef float f32x4 __attribute__((ext_vector_type(4)));

#define MFMA __builtin_amdgcn_mfma_f32_16x16x32_bf16

__device__ __forceinline__ float bf2f(unsigned short u) {
    unsigned int x = ((unsigned int)u) << 16;
    float f; __builtin_memcpy(&f, &x, 4); return f;
}
__device__ __forceinline__ unsigned short f2bf(float f) {
    unsigned int x; __builtin_memcpy(&x, &f, 4);
    unsigned int lsb = (x >> 16) & 1u;
    x += 0x7fffu + lsb;
    return (unsigned short)(x >> 16);
}

__device__ __forceinline__ void gload16(const void* g, void* l) {
    __builtin_amdgcn_global_load_lds(
        (const __attribute__((address_space(1))) unsigned int*)g,
        (__attribute__((address_space(3))) unsigned int*)l, 16, 0, 0);
}

// ---------------- fused prep: weight transforms + slots init ----------------
__global__ __launch_bounds__(256) void k_prep(
    const float* __restrict__ Wk, const float* __restrict__ Wv,
    const float* __restrict__ lnw, const float* __restrict__ lnb,
    const float* __restrict__ gWih, const float* __restrict__ gWhh,
    const float* __restrict__ W1, const float* __restrict__ W2,
    const float* __restrict__ Wq, const float* __restrict__ s0,
    unsigned short* __restrict__ wpk, float* __restrict__ cs, float* __restrict__ b2v,
    unsigned short* __restrict__ Wihbf, unsigned short* __restrict__ Whhbf,
    unsigned short* __restrict__ W1T, unsigned short* __restrict__ W2T,
    unsigned short* __restrict__ WqT, float* __restrict__ slots)
{
    const int blk = blockIdx.x, t = threadIdx.x;
    if (blk < 256) {                      // wpk subtiles (B-frag packed W')
        const int ct = blk >> 3, kt = blk & 7;
#pragma unroll
        for (int e2 = 0; e2 < 2; ++e2) {
            const int i = t * 2 + e2;
            const int lane = i >> 3, e = i & 7;
            const int col = ct * 16 + (lane & 15);
            const int k = kt * 32 + (lane >> 4) * 8 + e;
            const float wv = lnw[k];
            const float v = (col < 256) ? wv * Wk[(size_t)k * 256 + col] * SCALE
                                        : wv * Wv[(size_t)k * 256 + (col - 256)];
            wpk[(size_t)blk * 512 + i] = f2bf(v);
        }
    } else if (blk < 258) {               // cs (colsum of W') and b2 (ln_in_b @ W)
        const int c = (blk - 256) * 256 + t;
        float s1 = 0.f, s2 = 0.f;
        for (int k = 0; k < 256; ++k) {
            const float wraw = (c < 256) ? Wk[(size_t)k * 256 + c] * SCALE
                                         : Wv[(size_t)k * 256 + (c - 256)];
            s1 += lnw[k] * wraw;
            s2 += lnb[k] * wraw;
        }
        cs[c] = s1; b2v[c] = s2;
    } else if (blk < 1026) {              // Wih cvt
        const int i = (blk - 258) * 256 + t;
        Wihbf[i] = f2bf(gWih[i]);
    } else if (blk < 1794) {              // Whh cvt
        const int i = (blk - 1026) * 256 + t;
        Whhbf[i] = f2bf(gWhh[i]);
    } else if (blk < 2306) {              // W1T [512][256]
        const int nn = blk - 1794;
        W1T[(size_t)nn * 256 + t] = f2bf(W1[(size_t)t * 512 + nn]);
    } else if (blk < 2562) {              // W2T [256][512]
        const int nn = blk - 2306;
        W2T[(size_t)nn * 512 + t]       = f2bf(W2[(size_t)t * 256 + nn]);
        W2T[(size_t)nn * 512 + 256 + t] = f2bf(W2[(size_t)(256 + t) * 256 + nn]);
    } else if (blk < 2818) {              // WqT [256][256]
        const int nn = blk - 2562;
        WqT[(size_t)nn * 256 + t] = f2bf(Wq[(size_t)t * 256 + nn]);
    } else {                              // slots init (512 blocks)
        const int i = (blk - 2818) * 256 + t;
        slots[i] = s0[i];
    }
}

// ---------------- K1: K/V projection (R6 structure, 201us proven) -----------
// A: wave-private LDS raw bf16 (LN folded into epilogue). B: wpk packed frags
// staged via global_load_lds into 16KB dbuf (A region reused). 1 barrier/phase.
__global__ __launch_bounds__(256) void k1_mfma(
    const float* __restrict__ inp, const unsigned short* __restrict__ wpk,
    const float* __restrict__ cs, const float* __restrict__ b2v,
    unsigned short* __restrict__ kpk, unsigned short* __restrict__ vpk)
{
    __shared__ char smem[32768];
    char* abase = smem;                 // A region; becomes B dbuf after hoist
    char* bb0 = smem;
    char* bb1 = smem + 16384;
    const int t = threadIdx.x, w = t >> 6, l = t & 63;
    const size_t row0 = (size_t)blockIdx.x * 64;
    const int b_blk = blockIdx.x >> 6;
    const int kbase = (blockIdx.x & 63) * 64;
    const int lg = l >> 4;

    auto stageB = [&](int n2, char* dst) {
#pragma unroll
        for (int i = 0; i < 4; ++i) {
            const int seg = w * 4 + i;
            gload16((const char*)wpk + (size_t)n2 * 16384 + seg * 1024 + l * 16,
                    dst + seg * 1024);
        }
    };

    // ---- load raw rows, compute stats, pack raw bf16 to LDS (swizzled)
    float4 xv[16];
#pragma unroll
    for (int i = 0; i < 16; ++i)
        xv[i] = ((const float4*)(inp + (row0 + w * 16 + i) * D))[l];
    float rsA = 0.f, muA = 0.f;         // lane holds (rs, rs*mu) of row w*16+(l&15)
#pragma unroll
    for (int i = 0; i < 16; ++i) {
        const int r = w * 16 + i;
        const float4 x = xv[i];
        float s  = x.x + x.y + x.z + x.w;
        float ss = x.x*x.x + x.y*x.y + x.z*x.z + x.w*x.w;
#pragma unroll
        for (int off = 32; off; off >>= 1) { s += __shfl_xor(s, off); ss += __shfl_xor(ss, off); }
        const float mu = s * (1.f / 256.f);
        const float rs = rsqrtf(ss * (1.f / 256.f) - mu * mu + LNE);
        if ((l & 15) == i) { rsA = rs; muA = rs * mu; }
        ushort4 pk;
        pk.x = f2bf(x.x); pk.y = f2bf(x.y); pk.z = f2bf(x.z); pk.w = f2bf(x.w);
        *(ushort4*)(abase + r * 512 + ((l * 8) ^ ((r & 7) << 4))) = pk;
    }

    // ---- hoist A fragments (wave-private rows; no barrier needed)
    const int arow = w * 16 + (l & 15);
    const char* ap = abase + arow * 512;
    const int asw = (l & 7) << 4;
    bf16x8 af[8];
#pragma unroll
    for (int kk = 0; kk < 8; ++kk)
        af[kk] = *(const bf16x8*)(ap + ((kk * 64 + lg * 16) ^ asw));
    // V-half row stats (rows w*16 + lg*4 + r)
    float rsV[4], muV[4];
#pragma unroll
    for (int r = 0; r < 4; ++r) {
        rsV[r] = __shfl(rsA, lg * 4 + r);
        muV[r] = __shfl(muA, lg * 4 + r);
    }
    __syncthreads();                    // all hoists done; LDS repurposed to B dbuf
    stageB(0, bb0); stageB(1, bb1);
    __syncthreads();                    // both buffers landed

    const f32x4 fz = {0.f, 0.f, 0.f, 0.f};
    for (int n2 = 0; n2 < 16; ++n2) {
        const char* bbase = (n2 & 1) ? bb1 : bb0;
        f32x4 acc[2] = {fz, fz};
        if (n2 < 8) {
            // K half: swapped operands -> C[d][k]
#pragma unroll
            for (int kk = 0; kk < 8; ++kk) {
                const bf16x8 b0 = *(const bf16x8*)(bbase + kk * 1024 + l * 16);
                const bf16x8 b1 = *(const bf16x8*)(bbase + 8192 + kk * 1024 + l * 16);
                acc[0] = MFMA(b0, af[kk], acc[0], 0, 0, 0);
                acc[1] = MFMA(b1, af[kk], acc[1], 0, 0, 0);
            }
            const int kt16 = (kbase >> 4) + w;
#pragma unroll
            for (int nf = 0; nf < 2; ++nf) {
                const int d0 = n2 * 32 + nf * 16 + lg * 4;
                const float4 cs4 = *(const float4*)(cs + d0);
                const float4 bb4 = *(const float4*)(b2v + d0);
                unsigned short* kp = kpk
                    + ((((size_t)b_blk * 256 + kt16) * 8 + n2) * 512)
                    + ((l & 15) + ((nf * 2 + (lg >> 1)) << 4)) * 8 + (lg & 1) * 4;
                ushort4 pk;
                pk.x = f2bf(rsA * acc[nf][0] - muA * cs4.x + bb4.x);
                pk.y = f2bf(rsA * acc[nf][1] - muA * cs4.y + bb4.y);
                pk.z = f2bf(rsA * acc[nf][2] - muA * cs4.z + bb4.z);
                pk.w = f2bf(rsA * acc[nf][3] - muA * cs4.w + bb4.w);
                *(ushort4*)kp = pk;
            }
        } else {
            // V half: normal orientation -> C[k][d]
#pragma unroll
            for (int kk = 0; kk < 8; ++kk) {
                const bf16x8 b0 = *(const bf16x8*)(bbase + kk * 1024 + l * 16);
                const bf16x8 b1 = *(const bf16x8*)(bbase + 8192 + kk * 1024 + l * 16);
                acc[0] = MFMA(af[kk], b0, acc[0], 0, 0, 0);
                acc[1] = MFMA(af[kk], b1, acc[1], 0, 0, 0);
            }
            const int kt32 = (kbase >> 5) + (w >> 1);
#pragma unroll
            for (int nf = 0; nf < 2; ++nf) {
                const int c = n2 * 32 + nf * 16 + (l & 15);   // 256..511
                const float csc = cs[c], b2c = b2v[c];
                const int dt16 = (n2 - 8) * 2 + nf;
                unsigned short* vp = vpk
                    + ((((size_t)b_blk * 128 + kt32) * 16 + dt16) * 512)
                    + ((l & 15) + (((w & 1) * 2 + (lg >> 1)) << 4)) * 8 + (lg & 1) * 4;
                ushort4 pk;
                pk.x = f2bf(rsV[0] * acc[nf][0] - muV[0] * csc + b2c);
                pk.y = f2bf(rsV[1] * acc[nf][1] - muV[1] * csc + b2c);
                pk.z = f2bf(rsV[2] * acc[nf][2] - muV[2] * csc + b2c);
                pk.w = f2bf(rsV[3] * acc[nf][3] - muV[3] * csc + b2c);
                *(ushort4*)vp = pk;
            }
        }
        __syncthreads();                // buf reads done; stage(n2+1) landed
        if (n2 < 14) stageB(n2 + 2, (n2 & 1) ? bb1 : bb0);
    }
}

// ---------------- K2: LN(slots) + q projection (iter 0 only) ----------------
__global__ __launch_bounds__(256) void k2_qproj(
    const float* __restrict__ slots, const float* __restrict__ Wq,
    const float* __restrict__ lnw, const float* __restrict__ lnb, float* __restrict__ qbuf)
{
    const int row = blockIdx.x, t = threadIdx.x;
    __shared__ float sn[256];
    __shared__ float red[8];
    const float x = slots[(size_t)row * D + t];
    float mu, rs;
    {
        float s = x, ss = x * x;
#pragma unroll
        for (int off = 32; off; off >>= 1) { s += __shfl_xor(s, off); ss += __shfl_xor(ss, off); }
        if ((t & 63) == 0) { red[t >> 6] = s; red[4 + (t >> 6)] = ss; }
        __syncthreads();
        const float S  = red[0] + red[1] + red[2] + red[3];
        const float SS = red[4] + red[5] + red[6] + red[7];
        mu = S * (1.f / 256.f);
        rs = rsqrtf(SS * (1.f / 256.f) - mu * mu + LNE);
    }
    sn[t] = (x - mu) * rs * lnw[t] + lnb[t];
    __syncthreads();
    float acc = 0.f;
    for (int d = 0; d < 256; ++d) acc = fmaf(sn[d], Wq[(size_t)d * 256 + t], acc);
    qbuf[(size_t)row * D + t] = acc;
}

// ---------------- fused attention: R3 staged pipeline, packed layout --------
// grid = B*NCH (512); per block: 512 k-rows in 8 tiles of 64.
// K/V staged via global_load_lds (linear 1KB segs, no swizzle); psm single-buf.
__global__ __launch_bounds__(256) void k_attn(
    const unsigned short* __restrict__ kpk, const unsigned short* __restrict__ vpk,
    const float* __restrict__ qbuf, float* __restrict__ updp,
    float* __restrict__ denp, float* __restrict__ pbuf, int write_p)
{
    __shared__ unsigned short ksm[64 * 256];   // 32KB: 32 x 1KB subtiles [w][kk]
    __shared__ unsigned short vsm[64 * 256];   // 32KB: 32 x 1KB subtiles [kkp][dt16]
    __shared__ unsigned short psm[2048];       // 4KB P^T, swizzled
    __shared__ float dred[4][32];
    const int t = threadIdx.x, w = t >> 6, l = t & 63;
    const int b = blockIdx.x >> 3, chunk = blockIdx.x & 7;
    const int k0g = chunk * CHK;
    const int n = l & 15, lg = l >> 4;

    auto stage_ks = [&](int tile) {
        const char* src = (const char*)kpk
            + (((size_t)b * 256 + chunk * 32 + tile * 4) * 8) * 1024 + l * 16;
#pragma unroll
        for (int i = 0; i < 8; ++i) {
            const int seg = w * 8 + i;
            gload16(src + seg * 1024, (char*)ksm + seg * 1024);
        }
    };
    auto stage_vs = [&](int tile) {
        const char* src = (const char*)vpk
            + (((size_t)b * 128 + chunk * 16 + tile * 2) * 16) * 1024 + l * 16;
#pragma unroll
        for (int i = 0; i < 8; ++i) {
            const int seg = w * 8 + i;
            gload16(src + seg * 1024, (char*)vsm + seg * 1024);
        }
    };
    stage_ks(0); stage_vs(0);

    // q fragments (block-diagonal Q32)
    bf16x8 qf[2][2];
#pragma unroll
    for (int p = 0; p < 2; ++p) {
        const int h = p * 2 + (n >> 3);
        const float* qb = qbuf + ((size_t)b * Q + (n & 7)) * D;
#pragma unroll
        for (int j = 0; j < 2; ++j) {
            const int dbase = (h * 2 + j) * 32 + lg * 8;
            short tmp[8];
#pragma unroll
            for (int e = 0; e < 8; ++e) tmp[e] = (short)f2bf(qb[dbase + e]);
            __builtin_memcpy(&qf[p][j], tmp, 16);
        }
    }
    const bf16x8 ZV = {0,0,0,0,0,0,0,0};
    const f32x4 fz = {0.f,0.f,0.f,0.f};
    f32x4 pv[2][4];
#pragma unroll
    for (int mt = 0; mt < 2; ++mt)
#pragma unroll
        for (int nf = 0; nf < 4; ++nf) pv[mt][nf] = fz;
    float den0 = 0.f, den1 = 0.f;

    for (int tile = 0; tile < 8; ++tile) {
        __syncthreads();     // stage(tile) landed (incl. own-wave vmcnt drain)
        // ---- logits: K frags from ksm (linear)
        f32x4 lac[2] = {fz, fz};
#pragma unroll
        for (int kk = 0; kk < 8; ++kk) {
            const bf16x8 kf = *(const bf16x8*)((char*)ksm + (w * 8 + kk) * 1024 + l * 16);
            const int p = kk >> 2;
            const bool on = (((kk & 3) >> 1) == (n >> 3));
            const bf16x8 bq = on ? qf[p][kk & 1] : ZV;
            if (p == 0) lac[0] = MFMA(kf, bq, lac[0], 0, 0, 0);
            else        lac[1] = MFMA(kf, bq, lac[1], 0, 0, 0);
        }
        // ---- joint softmax over 32 (h,q) per k-row; no max-sub (|logit|~O(1))
#pragma unroll
        for (int reg = 0; reg < 4; ++reg) {
            const float e0 = __expf(lac[0][reg]);
            const float e1 = __expf(lac[1][reg]);
            float se = e0 + e1;
#pragma unroll
            for (int off = 8; off; off >>= 1) se += __shfl_xor(se, off);
            const float inv = 1.f / se;
            lac[0][reg] = e0 * inv; lac[1][reg] = e1 * inv;
            den0 += lac[0][reg];    den1 += lac[1][reg];
        }
        char* pb = (char*)psm;
        const int kb = w * 16 + lg * 4;
        {
            ushort4 p0, p1;
            p0.x = f2bf(lac[0][0]); p0.y = f2bf(lac[0][1]); p0.z = f2bf(lac[0][2]); p0.w = f2bf(lac[0][3]);
            p1.x = f2bf(lac[1][0]); p1.y = f2bf(lac[1][1]); p1.z = f2bf(lac[1][2]); p1.w = f2bf(lac[1][3]);
            *(ushort4*)(pb + n * 128 + ((kb * 2) ^ ((n & 7) << 4))) = p0;
            *(ushort4*)(pb + (16 + n) * 128 + ((kb * 2) ^ ((n & 7) << 4))) = p1;
        }
        if (write_p) {
            float* pp = pbuf + ((size_t)b * KK + k0g + tile * 64 + kb) * HQ;
#pragma unroll
            for (int reg = 0; reg < 4; ++reg) {
                pp[(size_t)reg * HQ + n] = lac[0][reg];
                pp[(size_t)reg * HQ + 16 + n] = lac[1][reg];
            }
        }
        __syncthreads();     // psm ready; ksm reads done
        if (tile < 7) stage_ks(tile + 1);
        // ---- PV: V frags from vsm (linear)
#pragma unroll
        for (int kkp = 0; kkp < 2; ++kkp) {
            const int koff = kkp * 64 + lg * 16;
            const bf16x8 a0 = *(const bf16x8*)(pb + n * 128 + (koff ^ ((n & 7) << 4)));
            const bf16x8 a1 = *(const bf16x8*)(pb + (16 + n) * 128 + (koff ^ ((n & 7) << 4)));
#pragma unroll
            for (int nf = 0; nf < 4; ++nf) {
                const bf16x8 bv = *(const bf16x8*)((char*)vsm + (kkp * 16 + w * 4 + nf) * 1024 + l * 16);
                pv[0][nf] = MFMA(a0, bv, pv[0][nf], 0, 0, 0);
                pv[1][nf] = MFMA(a1, bv, pv[1][nf], 0, 0, 0);
            }
        }
        __syncthreads();     // vsm/psm reads done
        if (tile < 7) stage_vs(tile + 1);
    }

    den0 += __shfl_xor(den0, 16); den0 += __shfl_xor(den0, 32);
    den1 += __shfl_xor(den1, 16); den1 += __shfl_xor(den1, 32);
    if (l < 16) { dred[w][l] = den0; dred[w][16 + l] = den1; }
    __syncthreads();
    if (t < 32)
        denp[((size_t)b * NCH + chunk) * HQ + t] =
            dred[0][t] + dred[1][t] + dred[2][t] + dred[3][t];

    if ((lg >> 1) == (w & 1)) {
        const int mt = w >> 1;
#pragma unroll
        for (int nf = 0; nf < 4; ++nf) {
#pragma unroll
            for (int reg = 0; reg < 4; ++reg) {
                const int q = (lg & 1) * 4 + reg;
                updp[(((size_t)b * NCH + chunk) * Q + q) * D + w * 64 + nf * 16 + n] = pv[mt][nf][reg];
            }
        }
    }
}

// ---------------- LN helper for k_slot ----------------
__device__ __forceinline__ void ln_rows(const f32x4 sv[4], char* dstA, float* red,
    const float* __restrict__ lnw, const float* __restrict__ lnb,
    int w, int n, int lg, int col0)
{
    float ps[4], pq[4];
#pragma unroll
    for (int r = 0; r < 4; ++r) {
        float s = 0.f, q2 = 0.f;
#pragma unroll
        for (int nf = 0; nf < 4; ++nf) { const float v = sv[nf][r]; s += v; q2 += v * v; }
#pragma unroll
        for (int off = 1; off < 16; off <<= 1) { s += __shfl_xor(s, off); q2 += __shfl_xor(q2, off); }
        ps[r] = s; pq[r] = q2;
    }
    if (n == 0) {
#pragma unroll
        for (int r = 0; r < 4; ++r) {
            red[(lg * 4 + r) * 8 + w * 2]     = ps[r];
            red[(lg * 4 + r) * 8 + w * 2 + 1] = pq[r];
        }
    }
    __syncthreads();
    float mu[4], rs[4];
#pragma unroll
    for (int r = 0; r < 4; ++r) {
        const int rowm = lg * 4 + r;
        const float S  = red[rowm*8+0] + red[rowm*8+2] + red[rowm*8+4] + red[rowm*8+6];
        const float SS = red[rowm*8+1] + red[rowm*8+3] + red[rowm*8+5] + red[rowm*8+7];
        mu[r] = S * (1.f / 256.f);
        rs[r] = rsqrtf(SS * (1.f / 256.f) - mu[r] * mu[r] + LNE);
    }
#pragma unroll
    for (int nf = 0; nf < 4; ++nf) {
        const int col = col0 + nf * 16;
        const float wv = lnw[col], bv = lnb[col];
#pragma unroll
        for (int r = 0; r < 4; ++r) {
            const int rowm = lg * 4 + r;
            const float mval = (sv[nf][r] - mu[r]) * rs[r] * wv + bv;
            *(unsigned short*)(dstA + rowm * 512 + ((col * 2) ^ ((rowm & 7) << 4))) = f2bf(mval);
        }
    }
}

// ---------------- fused slot update: reduce+GRU+LN+MLP+LN+qproj -------------
__global__ __launch_bounds__(256) void k_slot(
    const float* __restrict__ updp, const float* __restrict__ denp,
    float* __restrict__ slots,
    const unsigned short* __restrict__ Wihbf, const unsigned short* __restrict__ Whhbf,
    const float* __restrict__ bih, const float* __restrict__ bhh,
    const unsigned short* __restrict__ W1T, const float* __restrict__ b1,
    const unsigned short* __restrict__ W2T, const float* __restrict__ b2,
    const float* __restrict__ lnmw, const float* __restrict__ lnmb,
    const unsigned short* __restrict__ WqT,
    const float* __restrict__ lnsw, const float* __restrict__ lnsb,
    float* __restrict__ qbuf, float* __restrict__ outp)
{
    __shared__ char sm[34304];
    unsigned short* uA = (unsigned short*)(sm);
    unsigned short* hA = (unsigned short*)(sm + 8192);
    float* hf32        = (float*)(sm + 16384);
    char*  hidA        = sm + 16384;
    float* dsum        = (float*)(sm + 33280);
    float* red         = (float*)(sm + 33536);
    const int t = threadIdx.x, w = t >> 6, l = t & 63;
    const int n = l & 15, lg = l >> 4;
    const int R0 = blockIdx.x * 16;
    const f32x4 fz = {0.f, 0.f, 0.f, 0.f};

    {
        float us[16];
#pragma unroll
        for (int m = 0; m < 16; ++m) {
            const int gr = R0 + m, bb = gr >> 3, q = gr & 7;
            float s = 0.f;
#pragma unroll
            for (int c = 0; c < NCH; ++c)
                s += updp[(((size_t)(bb * NCH + c)) * Q + q) * D + t];
            us[m] = s;
        }
        if (t < 64) {
            const int m = t >> 2, h = t & 3;
            const int gr = R0 + m, bb = gr >> 3, q = gr & 7;
            float s = 0.f;
#pragma unroll
            for (int c = 0; c < NCH; ++c)
                s += denp[(size_t)(bb * NCH + c) * HQ + h * 8 + q];
            dsum[m * 4 + h] = s;
        }
#pragma unroll
        for (int m = 0; m < 16; ++m) {
            const float hv = slots[(size_t)(R0 + m) * 256 + t];
            hf32[m * 264 + t] = hv;
            *(unsigned short*)((char*)hA + m * 512 + ((t * 2) ^ ((m & 7) << 4))) = f2bf(hv);
        }
        __syncthreads();
        const int h = t >> 6;
#pragma unroll
        for (int m = 0; m < 16; ++m) {
            const float inv = 1.f / (dsum[m * 4 + h] + (float)KK * EPS);
            *(unsigned short*)((char*)uA + m * 512 + ((t * 2) ^ ((m & 7) << 4))) = f2bf(us[m] * inv);
        }
    }
    __syncthreads();

    f32x4 sv[4];
    {
        f32x4 ai0[4], ai1[4], ai2[4];
#pragma unroll
        for (int nf = 0; nf < 4; ++nf) { ai0[nf] = fz; ai1[nf] = fz; ai2[nf] = fz; }
#pragma unroll
        for (int kk = 0; kk < 8; ++kk) {
            const bf16x8 au = *(const bf16x8*)((char*)uA + n * 512 + ((kk * 64 + lg * 16) ^ ((n & 7) << 4)));
            const int kidx = kk * 32 + lg * 8;
#pragma unroll
            for (int nf = 0; nf < 4; ++nf) {
                const int col = w * 64 + nf * 16 + n;
                const bf16x8 br = *(const bf16x8*)(Wihbf + (size_t)col * 256 + kidx);
                const bf16x8 bz = *(const bf16x8*)(Wihbf + (size_t)(256 + col) * 256 + kidx);
                const bf16x8 bn = *(const bf16x8*)(Wihbf + (size_t)(512 + col) * 256 + kidx);
                ai0[nf] = MFMA(au, br, ai0[nf], 0, 0, 0);
                ai1[nf] = MFMA(au, bz, ai1[nf], 0, 0, 0);
                ai2[nf] = MFMA(au, bn, ai2[nf], 0, 0, 0);
            }
        }
        f32x4 ah0[4], ah1[4], ah2[4];
#pragma unroll
        for (int nf = 0; nf < 4; ++nf) { ah0[nf] = fz; ah1[nf] = fz; ah2[nf] = fz; }
#pragma unroll
        for (int kk = 0; kk < 8; ++kk) {
            const bf16x8 ah_ = *(const bf16x8*)((char*)hA + n * 512 + ((kk * 64 + lg * 16) ^ ((n & 7) << 4)));
            const int kidx = kk * 32 + lg * 8;
#pragma unroll
            for (int nf = 0; nf < 4; ++nf) {
                const int col = w * 64 + nf * 16 + n;
                const bf16x8 cr = *(const bf16x8*)(Whhbf + (size_t)col * 256 + kidx);
                const bf16x8 cz = *(const bf16x8*)(Whhbf + (size_t)(256 + col) * 256 + kidx);
                const bf16x8 cn = *(const bf16x8*)(Whhbf + (size_t)(512 + col) * 256 + kidx);
                ah0[nf] = MFMA(ah_, cr, ah0[nf], 0, 0, 0);
                ah1[nf] = MFMA(ah_, cz, ah1[nf], 0, 0, 0);
                ah2[nf] = MFMA(ah_, cn, ah2[nf], 0, 0, 0);
            }
        }
#pragma unroll
        for (int nf = 0; nf < 4; ++nf) {
            const int col = w * 64 + nf * 16 + n;
            const float br_ = bih[col], bz_ = bih[256 + col], bn_ = bih[512 + col];
            const float cr_ = bhh[col], cz_ = bhh[256 + col], cn_ = bhh[512 + col];
#pragma unroll
            for (int r = 0; r < 4; ++r) {
                const int rowm = lg * 4 + r;
                const float ir = ai0[nf][r] + br_, iz = ai1[nf][r] + bz_, inn = ai2[nf][r] + bn_;
                const float hr = ah0[nf][r] + cr_, hz = ah1[nf][r] + cz_, hn = ah2[nf][r] + cn_;
                const float rg = 1.f / (1.f + __expf(-(ir + hr)));
                const float zg = 1.f / (1.f + __expf(-(iz + hz)));
                const float ng = tanhf(inn + rg * hn);
                const float h0v = hf32[rowm * 264 + col];
                sv[nf][r] = (1.f - zg) * ng + zg * h0v;
            }
        }
    }
    ln_rows(sv, (char*)uA, red, lnmw, lnmb, w, n, lg, w * 64 + n);
    __syncthreads();

    {
        f32x4 m1[8];
#pragma unroll
        for (int nf = 0; nf < 8; ++nf) m1[nf] = fz;
#pragma unroll
        for (int kk = 0; kk < 8; ++kk) {
            const bf16x8 a = *(const bf16x8*)((char*)uA + n * 512 + ((kk * 64 + lg * 16) ^ ((n & 7) << 4)));
            const int kidx = kk * 32 + lg * 8;
#pragma unroll
            for (int nf = 0; nf < 8; ++nf) {
                const int colh = w * 128 + nf * 16 + n;
                const bf16x8 bb = *(const bf16x8*)(W1T + (size_t)colh * 256 + kidx);
                m1[nf] = MFMA(a, bb, m1[nf], 0, 0, 0);
            }
        }
        __syncthreads();
#pragma unroll
        for (int nf = 0; nf < 8; ++nf) {
            const int colh = w * 128 + nf * 16 + n;
            const float bb = b1[colh];
#pragma unroll
            for (int r = 0; r < 4; ++r) {
                const int rowm = lg * 4 + r;
                *(unsigned short*)(hidA + rowm * 1024 + ((colh * 2) ^ ((rowm & 7) << 4)))
                    = f2bf(fmaxf(m1[nf][r] + bb, 0.f));
            }
        }
    }
    __syncthreads();

    {
        f32x4 m2[4];
#pragma unroll
        for (int nf = 0; nf < 4; ++nf) m2[nf] = fz;
#pragma unroll
        for (int kk = 0; kk < 16; ++kk) {
            const bf16x8 a = *(const bf16x8*)(hidA + n * 1024 + ((kk * 64 + lg * 16) ^ ((n & 7) << 4)));
            const int kidx = kk * 32 + lg * 8;
#pragma unroll
            for (int nf = 0; nf < 4; ++nf) {
                const int col = w * 64 + nf * 16 + n;
                const bf16x8 bb = *(const bf16x8*)(W2T + (size_t)col * 512 + kidx);
                m2[nf] = MFMA(a, bb, m2[nf], 0, 0, 0);
            }
        }
#pragma unroll
        for (int nf = 0; nf < 4; ++nf) {
            const int col = w * 64 + nf * 16 + n;
            const float bb = b2[col];
#pragma unroll
            for (int r = 0; r < 4; ++r) {
                const int rowm = lg * 4 + r;
                const float v = m2[nf][r] + bb + sv[nf][r];
                sv[nf][r] = v;
                slots[(size_t)(R0 + rowm) * 256 + col] = v;
                if (outp) outp[(size_t)(R0 + rowm) * 256 + col] = v;
            }
        }
    }
    ln_rows(sv, (char*)hA, red, lnsw, lnsb, w, n, lg, w * 64 + n);
    __syncthreads();

    {
        f32x4 qa[4];
#pragma unroll
        for (int nf = 0; nf < 4; ++nf) qa[nf] = fz;
#pragma unroll
        for (int kk = 0; kk < 8; ++kk) {
            const bf16x8 a = *(const bf16x8*)((char*)hA + n * 512 + ((kk * 64 + lg * 16) ^ ((n & 7) << 4)));
            const int kidx = kk * 32 + lg * 8;
#pragma unroll
            for (int nf = 0; nf < 4; ++nf) {
                const int col = w * 64 + nf * 16 + n;
                const bf16x8 bb = *(const bf16x8*)(WqT + (size_t)col * 256 + kidx);
                qa[nf] = MFMA(a, bb, qa[nf], 0, 0, 0);
            }
        }
#pragma unroll
        for (int nf = 0; nf < 4; ++nf) {
            const int col = w * 64 + nf * 16 + n;
#pragma unroll
            for (int r = 0; r < 4; ++r)
                qbuf[(size_t)(R0 + lg * 4 + r) * 256 + col] = qa[nf][r];
        }
    }
}

// ---------------- attn output (invden computed inline) ----------------------
__global__ __launch_bounds__(256) void k7_attnout(
    const float* __restrict__ pbuf, const float* __restrict__ denp, float* __restrict__ out2)
{
    const int blk = blockIdx.x;
    const int b = blk >> 4;
    const int kk0 = (blk & 15) * 256;
    __shared__ float ps[256][33];
    __shared__ float inv[32];
    const int t = threadIdx.x;
    const float* pp = pbuf + ((size_t)b * KK + kk0) * HQ;
    for (int i = 0; i < 32; ++i) {
        const int idx = i * 256 + t;
        ps[idx >> 5][idx & 31] = pp[idx];
    }
    if (t < 32) {
        float s = 0.f;
#pragma unroll
        for (int c = 0; c < NCH; ++c) s += denp[((size_t)b * NCH + c) * HQ + t];
        inv[t] = 1.f / (s + (float)KK * EPS);
    }
    __syncthreads();
    float* o = out2 + (size_t)b * Q * KK + kk0 + t;
#pragma unroll
    for (int q = 0; q < 8; ++q) {
        float v = 0.f;
#pragma unroll
        for (int hh = 0; hh < 4; ++hh)
            v += (ps[t][hh * 8 + q] + EPS) * inv[hh * 8 + q];
        o[(size_t)q * KK] = v * 0.25f;
    }
}

extern "C" void kernel_launch(void* const* d_in, const int* in_sizes, int n_in,
                              void* d_out, int out_size, void* d_ws, size_t ws_size,
                              hipStream_t stream)
{
    const float* inputs  = (const float*)d_in[0];
    const float* slots0  = (const float*)d_in[1];
    const float* Wq      = (const float*)d_in[2];
    const float* Wk      = (const float*)d_in[3];
    const float* Wv      = (const float*)d_in[4];
    const float* ln_in_w = (const float*)d_in[5];
    const float* ln_in_b = (const float*)d_in[6];
    const float* ln_s_w  = (const float*)d_in[7];
    const float* ln_s_b  = (const float*)d_in[8];
    const float* ln_m_w  = (const float*)d_in[9];
    const float* ln_m_b  = (const float*)d_in[10];
    const float* gWih    = (const float*)d_in[11];
    const float* gWhh    = (const float*)d_in[12];
    const float* gbih    = (const float*)d_in[13];
    const float* gbhh    = (const float*)d_in[14];
    const float* W1      = (const float*)d_in[15];
    const float* b1      = (const float*)d_in[16];
    const float* W2      = (const float*)d_in[17];
    const float* b2      = (const float*)d_in[18];

    char* p = (char*)d_ws;
    unsigned short* kpk   = (unsigned short*)p; p += (size_t)B * KK * D * 2;
    unsigned short* vpk   = (unsigned short*)p; p += (size_t)B * KK * D * 2;
    float* pbuf   = (float*)p; p += (size_t)B * KK * HQ * 4;
    float* updp   = (float*)p; p += (size_t)B * NCH * Q * D * 4;
    float* denp   = (float*)p; p += (size_t)B * NCH * HQ * 4;
    float* qbuf   = (float*)p; p += (size_t)B * Q * D * 4;
    float* slots  = (float*)p; p += (size_t)B * Q * D * 4;
    unsigned short* wpk   = (unsigned short*)p; p += (size_t)512 * 256 * 2;
    float* csv    = (float*)p; p += 512 * 4;
    float* b2vv   = (float*)p; p += 512 * 4;
    unsigned short* Wihbf = (unsigned short*)p; p += (size_t)768 * 256 * 2;
    unsigned short* Whhbf = (unsigned short*)p; p += (size_t)768 * 256 * 2;
    unsigned short* W1T   = (unsigned short*)p; p += (size_t)HM * 256 * 2;
    unsigned short* W2T   = (unsigned short*)p; p += (size_t)256 * HM * 2;
    unsigned short* WqT   = (unsigned short*)p; p += (size_t)256 * 256 * 2;

    k_prep<<<3330, 256, 0, stream>>>(Wk, Wv, ln_in_w, ln_in_b, gWih, gWhh, W1, W2, Wq, slots0,
                                     wpk, csv, b2vv, Wihbf, Whhbf, W1T, W2T, WqT, slots);
    k1_mfma<<<(B * KK) / 64, 256, 0, stream>>>(inputs, wpk, csv, b2vv, kpk, vpk);
    k2_qproj<<<B * Q, 256, 0, stream>>>(slots, Wq, ln_s_w, ln_s_b, qbuf);
    for (int it = 0; it < 3; ++it) {
        k_attn<<<B * NCH, 256, 0, stream>>>(kpk, vpk, qbuf, updp, denp, pbuf, (it == 2) ? 1 : 0);
        k_slot<<<32, 256, 0, stream>>>(updp, denp, slots, Wihbf, Whhbf, gbih, gbhh,
                                       W1T, b1, W2T, b2, ln_m_w, ln_m_b, WqT,
                                       ln_s_w, ln_s_b, qbuf,
                                       (it == 2) ? (float*)d_out : (float*)nullptr);
    }
    k7_attnout<<<B * (KK / 256), 256, 0, stream>>>(pbuf, denp, (float*)d_out + (size_t)B * Q * D);
}

// Round 9
// 500.432 us; speedup vs baseline: 1.3396x; 1.1532x over previous
//
#include <hip/hip_runtime.h>

#define B   64
#define KK  4096
#define D   256
#define Q   8
#define H   4
#define DH  64
#define HQ  32
#define HM  512
#define NCH 8
#define CHK 512
#define EPS 1e-8f
#define LNE 1e-5f
#define SCALE 0.125f

typedef short bf16x8 __attribute__((ext_vector_type(8)));
typedef float f32x4 __attribute__((ext_vector_type(4)));

#define MFMA __builtin_amdgcn_mfma_f32_16x16x32_bf16

__device__ __forceinline__ float bf2f(unsigned short u) {
    unsigned int x = ((unsigned int)u) << 16;
    float f; __builtin_memcpy(&f, &x, 4); return f;
}
__device__ __forceinline__ unsigned short f2bf(float f) {
    unsigned int x; __builtin_memcpy(&x, &f, 4);
    unsigned int lsb = (x >> 16) & 1u;
    x += 0x7fffu + lsb;
    return (unsigned short)(x >> 16);
}

__device__ __forceinline__ void gload16(const void* g, void* l) {
    __builtin_amdgcn_global_load_lds(
        (const __attribute__((address_space(1))) unsigned int*)g,
        (__attribute__((address_space(3))) unsigned int*)l, 16, 0, 0);
}

// stage a [64 rows x 512B] bf16 tile into LDS, XOR-swizzled ((r&7)<<4), via
// global_load_lds with pre-swizzled source. 8 issues/wave, 2 rows per 1KB seg.
__device__ __forceinline__ void stage64x512B(const char* src, size_t row0,
                                             size_t stride, char* lds, int w, int l)
{
#pragma unroll
    for (int i = 0; i < 8; ++i) {
        const int seg = w * 8 + i;
        const int r = seg * 2 + (l >> 5);
        const int off = ((l & 31) * 16) ^ ((r & 7) << 4);
        gload16(src + (row0 + r) * stride + off, lds + seg * 1024);
    }
}

// ---------------- fused prep: weight transforms + slots init ----------------
__global__ __launch_bounds__(256) void k_prep(
    const float* __restrict__ Wk, const float* __restrict__ Wv,
    const float* __restrict__ lnw, const float* __restrict__ lnb,
    const float* __restrict__ gWih, const float* __restrict__ gWhh,
    const float* __restrict__ W1, const float* __restrict__ W2,
    const float* __restrict__ Wq, const float* __restrict__ s0,
    unsigned short* __restrict__ wpk, float* __restrict__ cs, float* __restrict__ b2v,
    unsigned short* __restrict__ Wihbf, unsigned short* __restrict__ Whhbf,
    unsigned short* __restrict__ W1T, unsigned short* __restrict__ W2T,
    float* __restrict__ slots, unsigned short* __restrict__ slots_bf)
{
    const int blk = blockIdx.x, t = threadIdx.x;
    if (blk < 256) {                      // wpk subtiles (B-frag packed W')
        const int ct = blk >> 3, kt = blk & 7;
#pragma unroll
        for (int e2 = 0; e2 < 2; ++e2) {
            const int i = t * 2 + e2;
            const int lane = i >> 3, e = i & 7;
            const int col = ct * 16 + (lane & 15);
            const int k = kt * 32 + (lane >> 4) * 8 + e;
            const float wv = lnw[k];
            const float v = (col < 256) ? wv * Wk[(size_t)k * 256 + col] * SCALE
                                        : wv * Wv[(size_t)k * 256 + (col - 256)];
            wpk[(size_t)blk * 512 + i] = f2bf(v);
        }
    } else if (blk < 258) {               // cs (colsum of W') and b2 (ln_in_b @ W)
        const int c = (blk - 256) * 256 + t;
        float s1 = 0.f, s2 = 0.f;
        for (int k = 0; k < 256; ++k) {
            const float wraw = (c < 256) ? Wk[(size_t)k * 256 + c] * SCALE
                                         : Wv[(size_t)k * 256 + (c - 256)];
            s1 += lnw[k] * wraw;
            s2 += lnb[k] * wraw;
        }
        cs[c] = s1; b2v[c] = s2;
    } else if (blk < 1026) {              // Wih cvt
        const int i = (blk - 258) * 256 + t;
        Wihbf[i] = f2bf(gWih[i]);
    } else if (blk < 1794) {              // Whh cvt
        const int i = (blk - 1026) * 256 + t;
        Whhbf[i] = f2bf(gWhh[i]);
    } else if (blk < 2306) {              // W1T [512][256]
        const int nn = blk - 1794;
        W1T[(size_t)nn * 256 + t] = f2bf(W1[(size_t)t * 512 + nn]);
    } else if (blk < 2562) {              // W2T [256][512]
        const int nn = blk - 2306;
        W2T[(size_t)nn * 512 + t]       = f2bf(W2[(size_t)t * 256 + nn]);
        W2T[(size_t)nn * 512 + 256 + t] = f2bf(W2[(size_t)(256 + t) * 256 + nn]);
    } else {                              // slots init (512 blocks)
        const int i = (blk - 2562) * 256 + t;
        const float v = s0[i];
        slots[i] = v; slots_bf[i] = f2bf(v);
    }
}

// ---------------- K1: K/V projection (R8 structure, 202us measured) ---------
__global__ __launch_bounds__(256) void k1_mfma(
    const float* __restrict__ inp, const unsigned short* __restrict__ wpk,
    const float* __restrict__ cs, const float* __restrict__ b2v,
    unsigned short* __restrict__ kpk, unsigned short* __restrict__ vpk)
{
    __shared__ char smem[32768];
    char* abase = smem;                 // A region; becomes B dbuf after hoist
    char* bb0 = smem;
    char* bb1 = smem + 16384;
    const int t = threadIdx.x, w = t >> 6, l = t & 63;
    const size_t row0 = (size_t)blockIdx.x * 64;
    const int b_blk = blockIdx.x >> 6;
    const int kbase = (blockIdx.x & 63) * 64;
    const int lg = l >> 4;

    auto stageB = [&](int n2, char* dst) {
#pragma unroll
        for (int i = 0; i < 4; ++i) {
            const int seg = w * 4 + i;
            gload16((const char*)wpk + (size_t)n2 * 16384 + seg * 1024 + l * 16,
                    dst + seg * 1024);
        }
    };

    float4 xv[16];
#pragma unroll
    for (int i = 0; i < 16; ++i)
        xv[i] = ((const float4*)(inp + (row0 + w * 16 + i) * D))[l];
    float rsA = 0.f, muA = 0.f;
#pragma unroll
    for (int i = 0; i < 16; ++i) {
        const int r = w * 16 + i;
        const float4 x = xv[i];
        float s  = x.x + x.y + x.z + x.w;
        float ss = x.x*x.x + x.y*x.y + x.z*x.z + x.w*x.w;
#pragma unroll
        for (int off = 32; off; off >>= 1) { s += __shfl_xor(s, off); ss += __shfl_xor(ss, off); }
        const float mu = s * (1.f / 256.f);
        const float rs = rsqrtf(ss * (1.f / 256.f) - mu * mu + LNE);
        if ((l & 15) == i) { rsA = rs; muA = rs * mu; }
        ushort4 pk;
        pk.x = f2bf(x.x); pk.y = f2bf(x.y); pk.z = f2bf(x.z); pk.w = f2bf(x.w);
        *(ushort4*)(abase + r * 512 + ((l * 8) ^ ((r & 7) << 4))) = pk;
    }

    const int arow = w * 16 + (l & 15);
    const char* ap = abase + arow * 512;
    const int asw = (l & 7) << 4;
    bf16x8 af[8];
#pragma unroll
    for (int kk = 0; kk < 8; ++kk)
        af[kk] = *(const bf16x8*)(ap + ((kk * 64 + lg * 16) ^ asw));
    float rsV[4], muV[4];
#pragma unroll
    for (int r = 0; r < 4; ++r) {
        rsV[r] = __shfl(rsA, lg * 4 + r);
        muV[r] = __shfl(muA, lg * 4 + r);
    }
    __syncthreads();
    stageB(0, bb0); stageB(1, bb1);
    __syncthreads();

    const f32x4 fz = {0.f, 0.f, 0.f, 0.f};
    for (int n2 = 0; n2 < 16; ++n2) {
        const char* bbase = (n2 & 1) ? bb1 : bb0;
        f32x4 acc[2] = {fz, fz};
        if (n2 < 8) {
#pragma unroll
            for (int kk = 0; kk < 8; ++kk) {
                const bf16x8 b0 = *(const bf16x8*)(bbase + kk * 1024 + l * 16);
                const bf16x8 b1 = *(const bf16x8*)(bbase + 8192 + kk * 1024 + l * 16);
                acc[0] = MFMA(b0, af[kk], acc[0], 0, 0, 0);
                acc[1] = MFMA(b1, af[kk], acc[1], 0, 0, 0);
            }
            const int kt16 = (kbase >> 4) + w;
#pragma unroll
            for (int nf = 0; nf < 2; ++nf) {
                const int d0 = n2 * 32 + nf * 16 + lg * 4;
                const float4 cs4 = *(const float4*)(cs + d0);
                const float4 bb4 = *(const float4*)(b2v + d0);
                unsigned short* kp = kpk
                    + ((((size_t)b_blk * 256 + kt16) * 8 + n2) * 512)
                    + ((l & 15) + ((nf * 2 + (lg >> 1)) << 4)) * 8 + (lg & 1) * 4;
                ushort4 pk;
                pk.x = f2bf(rsA * acc[nf][0] - muA * cs4.x + bb4.x);
                pk.y = f2bf(rsA * acc[nf][1] - muA * cs4.y + bb4.y);
                pk.z = f2bf(rsA * acc[nf][2] - muA * cs4.z + bb4.z);
                pk.w = f2bf(rsA * acc[nf][3] - muA * cs4.w + bb4.w);
                *(ushort4*)kp = pk;
            }
        } else {
#pragma unroll
            for (int kk = 0; kk < 8; ++kk) {
                const bf16x8 b0 = *(const bf16x8*)(bbase + kk * 1024 + l * 16);
                const bf16x8 b1 = *(const bf16x8*)(bbase + 8192 + kk * 1024 + l * 16);
                acc[0] = MFMA(af[kk], b0, acc[0], 0, 0, 0);
                acc[1] = MFMA(af[kk], b1, acc[1], 0, 0, 0);
            }
            const int kt32 = (kbase >> 5) + (w >> 1);
#pragma unroll
            for (int nf = 0; nf < 2; ++nf) {
                const int c = n2 * 32 + nf * 16 + (l & 15);
                const float csc = cs[c], b2c = b2v[c];
                const int dt16 = (n2 - 8) * 2 + nf;
                unsigned short* vp = vpk
                    + ((((size_t)b_blk * 128 + kt32) * 16 + dt16) * 512)
                    + ((l & 15) + (((w & 1) * 2 + (lg >> 1)) << 4)) * 8 + (lg & 1) * 4;
                ushort4 pk;
                pk.x = f2bf(rsV[0] * acc[nf][0] - muV[0] * csc + b2c);
                pk.y = f2bf(rsV[1] * acc[nf][1] - muV[1] * csc + b2c);
                pk.z = f2bf(rsV[2] * acc[nf][2] - muV[2] * csc + b2c);
                pk.w = f2bf(rsV[3] * acc[nf][3] - muV[3] * csc + b2c);
                *(ushort4*)vp = pk;
            }
        }
        __syncthreads();
        if (n2 < 14) stageB(n2 + 2, (n2 & 1) ? bb1 : bb0);
    }
}

// ---------------- K2: LN(slots) + q projection ----------------
__global__ __launch_bounds__(256) void k2_qproj(
    const float* __restrict__ slots, const float* __restrict__ Wq,
    const float* __restrict__ lnw, const float* __restrict__ lnb, float* __restrict__ qbuf)
{
    const int row = blockIdx.x, t = threadIdx.x;
    __shared__ float sn[256];
    __shared__ float red[8];
    const float x = slots[(size_t)row * D + t];
    float mu, rs;
    {
        float s = x, ss = x * x;
#pragma unroll
        for (int off = 32; off; off >>= 1) { s += __shfl_xor(s, off); ss += __shfl_xor(ss, off); }
        if ((t & 63) == 0) { red[t >> 6] = s; red[4 + (t >> 6)] = ss; }
        __syncthreads();
        const float S  = red[0] + red[1] + red[2] + red[3];
        const float SS = red[4] + red[5] + red[6] + red[7];
        mu = S * (1.f / 256.f);
        rs = rsqrtf(SS * (1.f / 256.f) - mu * mu + LNE);
    }
    sn[t] = (x - mu) * rs * lnw[t] + lnb[t];
    __syncthreads();
    float acc = 0.f;
    for (int d = 0; d < 256; ++d) acc = fmaf(sn[d], Wq[(size_t)d * 256 + t], acc);
    qbuf[(size_t)row * D + t] = acc;
}

// ---------------- fused attention (R8 structure, ~28us measured) ------------
__global__ __launch_bounds__(256) void k_attn(
    const unsigned short* __restrict__ kpk, const unsigned short* __restrict__ vpk,
    const float* __restrict__ qbuf, float* __restrict__ updp,
    float* __restrict__ denp, float* __restrict__ pbuf, int write_p)
{
    __shared__ unsigned short ksm[64 * 256];
    __shared__ unsigned short vsm[64 * 256];
    __shared__ unsigned short psm[2048];
    __shared__ float dred[4][32];
    const int t = threadIdx.x, w = t >> 6, l = t & 63;
    const int b = blockIdx.x >> 3, chunk = blockIdx.x & 7;
    const int k0g = chunk * CHK;
    const int n = l & 15, lg = l >> 4;

    auto stage_ks = [&](int tile) {
        const char* src = (const char*)kpk
            + (((size_t)b * 256 + chunk * 32 + tile * 4) * 8) * 1024 + l * 16;
#pragma unroll
        for (int i = 0; i < 8; ++i) {
            const int seg = w * 8 + i;
            gload16(src + seg * 1024, (char*)ksm + seg * 1024);
        }
    };
    auto stage_vs = [&](int tile) {
        const char* src = (const char*)vpk
            + (((size_t)b * 128 + chunk * 16 + tile * 2) * 16) * 1024 + l * 16;
#pragma unroll
        for (int i = 0; i < 8; ++i) {
            const int seg = w * 8 + i;
            gload16(src + seg * 1024, (char*)vsm + seg * 1024);
        }
    };
    stage_ks(0); stage_vs(0);

    bf16x8 qf[2][2];
#pragma unroll
    for (int p = 0; p < 2; ++p) {
        const int h = p * 2 + (n >> 3);
        const float* qb = qbuf + ((size_t)b * Q + (n & 7)) * D;
#pragma unroll
        for (int j = 0; j < 2; ++j) {
            const int dbase = (h * 2 + j) * 32 + lg * 8;
            short tmp[8];
#pragma unroll
            for (int e = 0; e < 8; ++e) tmp[e] = (short)f2bf(qb[dbase + e]);
            __builtin_memcpy(&qf[p][j], tmp, 16);
        }
    }
    const bf16x8 ZV = {0,0,0,0,0,0,0,0};
    const f32x4 fz = {0.f,0.f,0.f,0.f};
    f32x4 pv[2][4];
#pragma unroll
    for (int mt = 0; mt < 2; ++mt)
#pragma unroll
        for (int nf = 0; nf < 4; ++nf) pv[mt][nf] = fz;
    float den0 = 0.f, den1 = 0.f;

    for (int tile = 0; tile < 8; ++tile) {
        __syncthreads();
        f32x4 lac[2] = {fz, fz};
#pragma unroll
        for (int kk = 0; kk < 8; ++kk) {
            const bf16x8 kf = *(const bf16x8*)((char*)ksm + (w * 8 + kk) * 1024 + l * 16);
            const int p = kk >> 2;
            const bool on = (((kk & 3) >> 1) == (n >> 3));
            const bf16x8 bq = on ? qf[p][kk & 1] : ZV;
            if (p == 0) lac[0] = MFMA(kf, bq, lac[0], 0, 0, 0);
            else        lac[1] = MFMA(kf, bq, lac[1], 0, 0, 0);
        }
#pragma unroll
        for (int reg = 0; reg < 4; ++reg) {
            const float e0 = __expf(lac[0][reg]);
            const float e1 = __expf(lac[1][reg]);
            float se = e0 + e1;
#pragma unroll
            for (int off = 8; off; off >>= 1) se += __shfl_xor(se, off);
            const float inv = 1.f / se;
            lac[0][reg] = e0 * inv; lac[1][reg] = e1 * inv;
            den0 += lac[0][reg];    den1 += lac[1][reg];
        }
        char* pb = (char*)psm;
        const int kb = w * 16 + lg * 4;
        {
            ushort4 p0, p1;
            p0.x = f2bf(lac[0][0]); p0.y = f2bf(lac[0][1]); p0.z = f2bf(lac[0][2]); p0.w = f2bf(lac[0][3]);
            p1.x = f2bf(lac[1][0]); p1.y = f2bf(lac[1][1]); p1.z = f2bf(lac[1][2]); p1.w = f2bf(lac[1][3]);
            *(ushort4*)(pb + n * 128 + ((kb * 2) ^ ((n & 7) << 4))) = p0;
            *(ushort4*)(pb + (16 + n) * 128 + ((kb * 2) ^ ((n & 7) << 4))) = p1;
        }
        if (write_p) {
            float* pp = pbuf + ((size_t)b * KK + k0g + tile * 64 + kb) * HQ;
#pragma unroll
            for (int reg = 0; reg < 4; ++reg) {
                pp[(size_t)reg * HQ + n] = lac[0][reg];
                pp[(size_t)reg * HQ + 16 + n] = lac[1][reg];
            }
        }
        __syncthreads();
        if (tile < 7) stage_ks(tile + 1);
#pragma unroll
        for (int kkp = 0; kkp < 2; ++kkp) {
            const int koff = kkp * 64 + lg * 16;
            const bf16x8 a0 = *(const bf16x8*)(pb + n * 128 + (koff ^ ((n & 7) << 4)));
            const bf16x8 a1 = *(const bf16x8*)(pb + (16 + n) * 128 + (koff ^ ((n & 7) << 4)));
#pragma unroll
            for (int nf = 0; nf < 4; ++nf) {
                const bf16x8 bv = *(const bf16x8*)((char*)vsm + (kkp * 16 + w * 4 + nf) * 1024 + l * 16);
                pv[0][nf] = MFMA(a0, bv, pv[0][nf], 0, 0, 0);
                pv[1][nf] = MFMA(a1, bv, pv[1][nf], 0, 0, 0);
            }
        }
        __syncthreads();
        if (tile < 7) stage_vs(tile + 1);
    }

    den0 += __shfl_xor(den0, 16); den0 += __shfl_xor(den0, 32);
    den1 += __shfl_xor(den1, 16); den1 += __shfl_xor(den1, 32);
    if (l < 16) { dred[w][l] = den0; dred[w][16 + l] = den1; }
    __syncthreads();
    if (t < 32)
        denp[((size_t)b * NCH + chunk) * HQ + t] =
            dred[0][t] + dred[1][t] + dred[2][t] + dred[3][t];

    if ((lg >> 1) == (w & 1)) {
        const int mt = w >> 1;
#pragma unroll
        for (int nf = 0; nf < 4; ++nf) {
#pragma unroll
            for (int reg = 0; reg < 4; ++reg) {
                const int q = (lg & 1) * 4 + reg;
                updp[(((size_t)b * NCH + chunk) * Q + q) * D + w * 64 + nf * 16 + n] = pv[mt][nf][reg];
            }
        }
    }
}

// ---------------- reduce partials -> upd_bf (renormalized) — R3 proven ------
__global__ __launch_bounds__(256) void k_reduce(
    const float* __restrict__ updp, const float* __restrict__ denp,
    unsigned short* __restrict__ updbf)
{
    const int row = blockIdx.x, t = threadIdx.x;
    const int b = row >> 3, q = row & 7, h = t >> 6;
    float ds = 0.f, us = 0.f;
#pragma unroll
    for (int c = 0; c < NCH; ++c) {
        ds += denp[((size_t)b * NCH + c) * HQ + h * Q + q];
        us += updp[(((size_t)b * NCH + c) * Q + q) * D + t];
    }
    updbf[(size_t)row * D + t] = f2bf(us / (ds + (float)KK * EPS));
}

// ---------------- GRU gemm: gg[512][1536] = [u|h] @ [Wih;Whh]^T — R3 proven -
__global__ __launch_bounds__(256) void k_gru(
    const unsigned short* __restrict__ updbf, const unsigned short* __restrict__ slotsbf,
    const unsigned short* __restrict__ Wihbf, const unsigned short* __restrict__ Whhbf,
    float* __restrict__ gg)
{
    __shared__ unsigned short As[64 * 256];
    __shared__ unsigned short Bs[64 * 256];
    const int t = threadIdx.x, w = t >> 6, l = t & 63;
    const int rb = blockIdx.x / 24, nb = blockIdx.x % 24;
    const unsigned short* Asrc = (nb < 12) ? updbf : slotsbf;
    stage64x512B((const char*)Asrc, (size_t)rb * 64, 512, (char*)As, w, l);
    if (nb < 12) stage64x512B((const char*)Wihbf, (size_t)nb * 64, 512, (char*)Bs, w, l);
    else         stage64x512B((const char*)Whhbf, (size_t)(nb - 12) * 64, 512, (char*)Bs, w, l);
    __syncthreads();
    const int arow = w * 16 + (l & 15);
    const int asw = (l & 7) << 4;
    bf16x8 af[8];
#pragma unroll
    for (int kk = 0; kk < 8; ++kk)
        af[kk] = *(const bf16x8*)((char*)As + arow * 512 + ((kk * 64 + (l >> 4) * 16) ^ asw));
    const f32x4 fz = {0.f,0.f,0.f,0.f};
    f32x4 acc[4] = {fz, fz, fz, fz};
#pragma unroll
    for (int kk = 0; kk < 8; ++kk) {
        const int koff = kk * 64 + (l >> 4) * 16;
#pragma unroll
        for (int nf = 0; nf < 4; ++nf) {
            const int brow = nf * 16 + (l & 15);
            const bf16x8 bf_ = *(const bf16x8*)((char*)Bs + brow * 512 + (koff ^ ((brow & 7) << 4)));
            acc[nf] = MFMA(af[kk], bf_, acc[nf], 0, 0, 0);
        }
    }
    const int colbase = (nb < 12) ? nb * 64 : 768 + (nb - 12) * 64;
#pragma unroll
    for (int nf = 0; nf < 4; ++nf) {
        const int col = colbase + nf * 16 + (l & 15);
#pragma unroll
        for (int reg = 0; reg < 4; ++reg) {
            const size_t row = (size_t)rb * 64 + w * 16 + (l >> 4) * 4 + reg;
            gg[row * 1536 + col] = acc[nf][reg];
        }
    }
}

// ---------------- gates + LN(mlp) — R3 proven ----------------
__global__ __launch_bounds__(256) void k_gates(
    const float* __restrict__ gg, const float* __restrict__ slots,
    const float* __restrict__ bih, const float* __restrict__ bhh,
    const float* __restrict__ lnw, const float* __restrict__ lnb,
    float* __restrict__ snew, unsigned short* __restrict__ mbf)
{
    const int row = blockIdx.x, t = threadIdx.x;
    __shared__ float red[8];
    const float* g = gg + (size_t)row * 1536;
    const float i_r = g[t]        + bih[t];
    const float i_z = g[256 + t]  + bih[256 + t];
    const float i_n = g[512 + t]  + bih[512 + t];
    const float h_r = g[768 + t]  + bhh[t];
    const float h_z = g[1024 + t] + bhh[256 + t];
    const float h_n = g[1280 + t] + bhh[512 + t];
    const float r = 1.f / (1.f + __expf(-(i_r + h_r)));
    const float z = 1.f / (1.f + __expf(-(i_z + h_z)));
    const float nn = tanhf(i_n + r * h_n);
    const float h0 = slots[(size_t)row * D + t];
    const float sn = (1.f - z) * nn + z * h0;
    snew[(size_t)row * D + t] = sn;
    float mu, rs;
    {
        float s = sn, ss = sn * sn;
#pragma unroll
        for (int off = 32; off; off >>= 1) { s += __shfl_xor(s, off); ss += __shfl_xor(ss, off); }
        if ((t & 63) == 0) { red[t >> 6] = s; red[4 + (t >> 6)] = ss; }
        __syncthreads();
        const float S  = red[0] + red[1] + red[2] + red[3];
        const float SS = red[4] + red[5] + red[6] + red[7];
        mu = S * (1.f / 256.f);
        rs = rsqrtf(SS * (1.f / 256.f) - mu * mu + LNE);
    }
    mbf[(size_t)row * D + t] = f2bf((sn - mu) * rs * lnw[t] + lnb[t]);
}

// ---------------- MLP gemm 1: hid = relu(m @ W1 + b1) — R3 proven -----------
__global__ __launch_bounds__(256) void k_mlp1(
    const unsigned short* __restrict__ mbf, const unsigned short* __restrict__ W1T,
    const float* __restrict__ b1, unsigned short* __restrict__ hidbf)
{
    __shared__ unsigned short As[64 * 256];
    __shared__ unsigned short Bs[64 * 256];
    const int t = threadIdx.x, w = t >> 6, l = t & 63;
    const int rb = blockIdx.x >> 3, nb = blockIdx.x & 7;
    stage64x512B((const char*)mbf, (size_t)rb * 64, 512, (char*)As, w, l);
    stage64x512B((const char*)W1T, (size_t)nb * 64, 512, (char*)Bs, w, l);
    __syncthreads();
    const int arow = w * 16 + (l & 15);
    const int asw = (l & 7) << 4;
    bf16x8 af[8];
#pragma unroll
    for (int kk = 0; kk < 8; ++kk)
        af[kk] = *(const bf16x8*)((char*)As + arow * 512 + ((kk * 64 + (l >> 4) * 16) ^ asw));
    const f32x4 fz = {0.f,0.f,0.f,0.f};
    f32x4 acc[4] = {fz, fz, fz, fz};
#pragma unroll
    for (int kk = 0; kk < 8; ++kk) {
        const int koff = kk * 64 + (l >> 4) * 16;
#pragma unroll
        for (int nf = 0; nf < 4; ++nf) {
            const int brow = nf * 16 + (l & 15);
            const bf16x8 bf_ = *(const bf16x8*)((char*)Bs + brow * 512 + (koff ^ ((brow & 7) << 4)));
            acc[nf] = MFMA(af[kk], bf_, acc[nf], 0, 0, 0);
        }
    }
#pragma unroll
    for (int nf = 0; nf < 4; ++nf) {
        const int col = nb * 64 + nf * 16 + (l & 15);
        const float bb = b1[col];
#pragma unroll
        for (int reg = 0; reg < 4; ++reg) {
            const size_t row = (size_t)rb * 64 + w * 16 + (l >> 4) * 4 + reg;
            hidbf[row * HM + col] = f2bf(fmaxf(acc[nf][reg] + bb, 0.f));
        }
    }
}

// ---------------- MLP gemm 2 + residual -> slots — R3 proven ----------------
__global__ __launch_bounds__(256) void k_mlp2(
    const unsigned short* __restrict__ hidbf, const unsigned short* __restrict__ W2T,
    const float* __restrict__ b2, const float* __restrict__ snew,
    float* __restrict__ slots, unsigned short* __restrict__ slotsbf,
    float* __restrict__ outp)
{
    __shared__ unsigned short As[64 * 256];
    __shared__ unsigned short Bs[64 * 256];
    const int t = threadIdx.x, w = t >> 6, l = t & 63;
    const int rb = blockIdx.x >> 2, nb = blockIdx.x & 3;
    const f32x4 fz = {0.f,0.f,0.f,0.f};
    f32x4 acc[4] = {fz, fz, fz, fz};
    for (int c = 0; c < 2; ++c) {
        stage64x512B((const char*)hidbf + c * 512, (size_t)rb * 64, 1024, (char*)As, w, l);
        stage64x512B((const char*)W2T + c * 512, (size_t)nb * 64, 1024, (char*)Bs, w, l);
        __syncthreads();
        const int arow = w * 16 + (l & 15);
        const int asw = (l & 7) << 4;
        bf16x8 af[8];
#pragma unroll
        for (int kk = 0; kk < 8; ++kk)
            af[kk] = *(const bf16x8*)((char*)As + arow * 512 + ((kk * 64 + (l >> 4) * 16) ^ asw));
#pragma unroll
        for (int kk = 0; kk < 8; ++kk) {
            const int koff = kk * 64 + (l >> 4) * 16;
#pragma unroll
            for (int nf = 0; nf < 4; ++nf) {
                const int brow = nf * 16 + (l & 15);
                const bf16x8 bf_ = *(const bf16x8*)((char*)Bs + brow * 512 + (koff ^ ((brow & 7) << 4)));
                acc[nf] = MFMA(af[kk], bf_, acc[nf], 0, 0, 0);
            }
        }
        __syncthreads();
    }
#pragma unroll
    for (int nf = 0; nf < 4; ++nf) {
        const int col = nb * 64 + nf * 16 + (l & 15);
        const float bb = b2[col];
#pragma unroll
        for (int reg = 0; reg < 4; ++reg) {
            const size_t row = (size_t)rb * 64 + w * 16 + (l >> 4) * 4 + reg;
            const float v = snew[row * D + col] + acc[nf][reg] + bb;
            slots[row * D + col] = v;
            slotsbf[row * D + col] = f2bf(v);
            if (outp) outp[row * D + col] = v;
        }
    }
}

// ---------------- attn output (invden computed inline) ----------------------
__global__ __launch_bounds__(256) void k7_attnout(
    const float* __restrict__ pbuf, const float* __restrict__ denp, float* __restrict__ out2)
{
    const int blk = blockIdx.x;
    const int b = blk >> 4;
    const int kk0 = (blk & 15) * 256;
    __shared__ float ps[256][33];
    __shared__ float inv[32];
    const int t = threadIdx.x;
    const float* pp = pbuf + ((size_t)b * KK + kk0) * HQ;
    for (int i = 0; i < 32; ++i) {
        const int idx = i * 256 + t;
        ps[idx >> 5][idx & 31] = pp[idx];
    }
    if (t < 32) {
        float s = 0.f;
#pragma unroll
        for (int c = 0; c < NCH; ++c) s += denp[((size_t)b * NCH + c) * HQ + t];
        inv[t] = 1.f / (s + (float)KK * EPS);
    }
    __syncthreads();
    float* o = out2 + (size_t)b * Q * KK + kk0 + t;
#pragma unroll
    for (int q = 0; q < 8; ++q) {
        float v = 0.f;
#pragma unroll
        for (int hh = 0; hh < 4; ++hh)
            v += (ps[t][hh * 8 + q] + EPS) * inv[hh * 8 + q];
        o[(size_t)q * KK] = v * 0.25f;
    }
}

extern "C" void kernel_launch(void* const* d_in, const int* in_sizes, int n_in,
                              void* d_out, int out_size, void* d_ws, size_t ws_size,
                              hipStream_t stream)
{
    const float* inputs  = (const float*)d_in[0];
    const float* slots0  = (const float*)d_in[1];
    const float* Wq      = (const float*)d_in[2];
    const float* Wk      = (const float*)d_in[3];
    const float* Wv      = (const float*)d_in[4];
    const float* ln_in_w = (const float*)d_in[5];
    const float* ln_in_b = (const float*)d_in[6];
    const float* ln_s_w  = (const float*)d_in[7];
    const float* ln_s_b  = (const float*)d_in[8];
    const float* ln_m_w  = (const float*)d_in[9];
    const float* ln_m_b  = (const float*)d_in[10];
    const float* gWih    = (const float*)d_in[11];
    const float* gWhh    = (const float*)d_in[12];
    const float* gbih    = (const float*)d_in[13];
    const float* gbhh    = (const float*)d_in[14];
    const float* W1      = (const float*)d_in[15];
    const float* b1      = (const float*)d_in[16];
    const float* W2      = (const float*)d_in[17];
    const float* b2      = (const float*)d_in[18];

    char* p = (char*)d_ws;
    unsigned short* kpk   = (unsigned short*)p; p += (size_t)B * KK * D * 2;
    unsigned short* vpk   = (unsigned short*)p; p += (size_t)B * KK * D * 2;
    float* pbuf   = (float*)p; p += (size_t)B * KK * HQ * 4;
    float* updp   = (float*)p; p += (size_t)B * NCH * Q * D * 4;   // gg aliases
    float* denp   = (float*)p; p += (size_t)B * NCH * HQ * 4;
    float* qbuf   = (float*)p; p += (size_t)B * Q * D * 4;
    float* slots  = (float*)p; p += (size_t)B * Q * D * 4;
    float* snew   = (float*)p; p += (size_t)B * Q * D * 4;
    unsigned short* slots_bf = (unsigned short*)p; p += (size_t)B * Q * D * 2;
    unsigned short* upd_bf   = (unsigned short*)p; p += (size_t)B * Q * D * 2;
    unsigned short* mbf      = (unsigned short*)p; p += (size_t)B * Q * D * 2;
    unsigned short* hidbf    = (unsigned short*)p; p += (size_t)B * Q * HM * 2;
    unsigned short* wpk   = (unsigned short*)p; p += (size_t)512 * 256 * 2;
    float* csv    = (float*)p; p += 512 * 4;
    float* b2vv   = (float*)p; p += 512 * 4;
    unsigned short* Wihbf = (unsigned short*)p; p += (size_t)768 * 256 * 2;
    unsigned short* Whhbf = (unsigned short*)p; p += (size_t)768 * 256 * 2;
    unsigned short* W1T   = (unsigned short*)p; p += (size_t)HM * 256 * 2;
    unsigned short* W2T   = (unsigned short*)p; p += (size_t)256 * HM * 2;
    float* gg = updp;   // alias: gg[512][1536] (3.1MB) < updp (4.2MB); lifetimes disjoint

    k_prep<<<3074, 256, 0, stream>>>(Wk, Wv, ln_in_w, ln_in_b, gWih, gWhh, W1, W2, Wq, slots0,
                                     wpk, csv, b2vv, Wihbf, Whhbf, W1T, W2T, slots, slots_bf);
    k1_mfma<<<(B * KK) / 64, 256, 0, stream>>>(inputs, wpk, csv, b2vv, kpk, vpk);
    k2_qproj<<<B * Q, 256, 0, stream>>>(slots, Wq, ln_s_w, ln_s_b, qbuf);
    for (int it = 0; it < 3; ++it) {
        k_attn<<<B * NCH, 256, 0, stream>>>(kpk, vpk, qbuf, updp, denp, pbuf, (it == 2) ? 1 : 0);
        k_reduce<<<B * Q, 256, 0, stream>>>(updp, denp, upd_bf);
        k_gru<<<8 * 24, 256, 0, stream>>>(upd_bf, slots_bf, Wihbf, Whhbf, gg);
        k_gates<<<B * Q, 256, 0, stream>>>(gg, slots, gbih, gbhh, ln_m_w, ln_m_b, snew, mbf);
        k_mlp1<<<8 * 8, 256, 0, stream>>>(mbf, W1T, b1, hidbf);
        k_mlp2<<<8 * 4, 256, 0, stream>>>(hidbf, W2T, b2, snew, slots, slots_bf,
                                          (it == 2) ? (float*)d_out : (float*)nullptr);
        if (it < 2)
            k2_qproj<<<B * Q, 256, 0, stream>>>(slots, Wq, ln_s_w, ln_s_b, qbuf);
    }
    k7_attnout<<<B * (KK / 256), 256, 0, stream>>>(pbuf, denp, (float*)d_out + (size_t)B * Q * D);
}